// Round 5
// baseline (3047.610 us; speedup 1.0000x reference)
//
#include <hip/hip_runtime.h>
#include <hip/hip_bf16.h>
#include <stdint.h>

typedef __bf16 bf;
typedef __bf16 bfv8 __attribute__((ext_vector_type(8)));
typedef __bf16 bfv4 __attribute__((ext_vector_type(4)));
typedef float  f32x4 __attribute__((ext_vector_type(4)));

#define MFMA16(a,b,c) __builtin_amdgcn_mfma_f32_16x16x32_bf16((a),(b),(c),0,0,0)

#define CH  96
#define WID 256
#define HGT 256
#define NB  8
#define SCALE 0.1020620726159658f   // 96^-0.5

__device__ __forceinline__ float b2f(bf x){ return (float)x; }
__device__ __forceinline__ bf   f2b(float x){ return (bf)x; }

__device__ __forceinline__ bfv8 ld_cvt8(const float* __restrict__ p){
  f32x4 a = *(const f32x4*)p;
  f32x4 b = *(const f32x4*)(p + 4);
  bfv8 r;
  r[0]=f2b(a[0]); r[1]=f2b(a[1]); r[2]=f2b(a[2]); r[3]=f2b(a[3]);
  r[4]=f2b(b[0]); r[5]=f2b(b[1]); r[6]=f2b(b[2]); r[7]=f2b(b[3]);
  return r;
}

// ---------------- K1: dual fused conv1x1 (MFMA) + depthwise 3x3 ----------------
#define TW 64
#define TH 2
#define HC 66
#define HROWS 264
#define TSTR 96

__global__ __launch_bounds__(256) void k_proj2(
    const float* __restrict__ X,
    const float* __restrict__ W1a, const float* __restrict__ B1a,
    const float* __restrict__ WDa, const float* __restrict__ BDa, bf* __restrict__ Oa,
    const float* __restrict__ W1b, const float* __restrict__ B1b,
    const float* __restrict__ WDb, const float* __restrict__ BDb, bf* __restrict__ Ob)
{
  extern __shared__ bf tile[];  // [264][96] = 50,688 B
  const int tid=threadIdx.x, lane=tid&63, wid=tid>>6;
  const int l15=lane&15, lg=lane>>4;
  const int gx=blockIdx.x*TW, gy=blockIdx.y*TH, b=blockIdx.z;
  const size_t ibase=(size_t)b*(HGT*WID)*CH;

  bfv8 af[5][3];
#pragma unroll
  for (int i=0;i<5;++i){
    int mt=wid+i*4;
    int p=mt*16+l15;
    int hr=p/HC, hcc=p%HC;
    int y=gy-1+hr, x=gx-1+hcc;
    bool inb=(mt<17)&&(p<HROWS)&&(y>=0)&&(y<HGT)&&(x>=0)&&(x<WID);
#pragma unroll
    for (int ks=0;ks<3;++ks){
      bfv8 v={0,0,0,0,0,0,0,0};
      if (inb) v=ld_cvt8(X+ibase+((size_t)y*WID+x)*CH+ks*32+lg*8);
      af[i][ks]=v;
    }
  }

#pragma unroll 1
  for (int pass=0; pass<2; ++pass){
    const float* W1 = pass?W1b:W1a;
    const float* B1 = pass?B1b:B1a;
    const float* WD = pass?WDb:WDa;
    const float* BD = pass?BDb:BDa;
    bf* O = pass?Ob:Oa;
    if (pass) __syncthreads();
    {
      bfv8 wf[6][3];
      float bias[6];
#pragma unroll
      for (int nt=0;nt<6;++nt){
        bias[nt]=B1[nt*16+l15];
#pragma unroll
        for (int ks=0;ks<3;++ks) wf[nt][ks]=ld_cvt8(W1+(nt*16+l15)*CH+ks*32+lg*8);
      }
#pragma unroll
      for (int i=0;i<5;++i){
        int mt=wid+i*4;
        if (mt>=17) continue;
        f32x4 acc[6];
#pragma unroll
        for (int nt=0;nt<6;++nt) acc[nt]=(f32x4){bias[nt],bias[nt],bias[nt],bias[nt]};
#pragma unroll
        for (int ks=0;ks<3;++ks)
#pragma unroll
          for (int nt=0;nt<6;++nt) acc[nt]=MFMA16(af[i][ks],wf[nt][ks],acc[nt]);
        int prow=mt*16+lg*4;
#pragma unroll
        for (int r=0;r<4;++r){
          int pp=prow+r;
          if (pp<HROWS){
            int hr2=pp/HC,hc2=pp%HC;
            int yy=gy-1+hr2, xx=gx-1+hc2;
            bool ib=(yy>=0)&&(yy<HGT)&&(xx>=0)&&(xx<WID);
#pragma unroll
            for (int nt=0;nt<6;++nt) tile[pp*TSTR+nt*16+l15]=f2b(ib?acc[nt][r]:0.f);
          }
        }
      }
    }
    __syncthreads();
    if (tid<252){
      int g=tid%12, pi0=tid/12;
      float w9[8][9], bb[8];
#pragma unroll
      for (int j=0;j<8;++j){
#pragma unroll
        for (int t=0;t<9;++t) w9[j][t]=WD[(g*8+j)*9+t];
        bb[j]=BD[g*8+j];
      }
      for (int pi=pi0; pi<TW*TH; pi+=21){
        int oy=pi/TW, ox=pi%TW;
        int y=gy+oy;
        float acc[8];
#pragma unroll
        for (int j=0;j<8;++j) acc[j]=bb[j];
#pragma unroll
        for (int dy=0;dy<3;++dy)
#pragma unroll
          for (int dx=0;dx<3;++dx){
            bfv8 v8=*(const bfv8*)(tile+((oy+dy)*HC+(ox+dx))*TSTR+g*8);
#pragma unroll
            for (int j=0;j<8;++j) acc[j]+=w9[j][dy*3+dx]*b2f(v8[j]);
          }
        bf* dst=O+ibase+((size_t)y*WID+gx+ox)*CH+g*8;
        bfv8 st;
#pragma unroll
        for (int j=0;j<8;++j) st[j]=f2b(acc[j]);
        *(bfv8*)dst=st;
      }
    }
  }
}

// ---------------- K_vt: in-place per-(b,h)-row transpose [v][c] -> [c][v] ----------------
__global__ __launch_bounds__(256) void k_vt(bf* Vl, bf* Vr)
{
  __shared__ bf vt2[96*264];
  const int tid = threadIdx.x, lane = tid & 63, wid = tid >> 6;
  bf* V = (blockIdx.y ? Vr : Vl) + (size_t)blockIdx.x * (WID*CH);
  {
    const bfv8* src = (const bfv8*)(V + (size_t)tid*CH);
#pragma unroll
    for (int i=0;i<12;++i){ bfv8 v8 = src[i];
#pragma unroll
      for (int j=0;j<8;++j) vt2[(i*8+j)*264 + tid] = v8[j]; }
  }
  __syncthreads();
  for (int c = wid; c < CH; c += 4)
    *(bfv4*)(V + c*WID + lane*4) = *(const bfv4*)(vt2 + c*264 + lane*4);
}

// ---------------- K_attn: fused scores+softmax+apply, chunked (low-VGPR) ----------------
// phase 0: S = Ql Qr^T in 2x128-col chunks; aq <- exp(S) UNSCALED; rowsum in regs;
//          F_r2l = (aq @ Vr) * (SCALE/rowsum) per output row (deferred scale).
// phase 1: S^T = Qr Ql^T chunks; aq <- exp(S^T) * fw[col] (fw = SCALE/rs from LDS);
//          F_l2r = aq @ Vl.
// F staged through wave-private aq rows -> fully coalesced 192B-per-pixel stores.
__global__ __launch_bounds__(256,4) void k_attn(
    const bf* __restrict__ Ql, const bf* __restrict__ Qr,
    const bf* __restrict__ Vlt, const bf* __restrict__ Vrt,
    bf* __restrict__ Fout)
{
  extern __shared__ char sm[];
  bf* aq = (bf*)sm;                       // [64][264]
  float* rs = (float*)(sm + 64*264*2);    // [256], becomes fw after phase 0
  const int tid=threadIdx.x, lane=tid&63, wid=tid>>6;
  const int l15=lane&15, lg=lane>>4;
  const int bh = blockIdx.x;
  const size_t qoff = (size_t)bh * (WID*CH);

#pragma unroll 1
  for (int phase=0; phase<2; ++phase) {
    const bf* msrc = phase ? Qr + qoff : Ql + qoff;
    const bf* nsrc = phase ? Ql + qoff : Qr + qoff;
    const bf* vt   = (phase ? Vlt : Vrt) + qoff;
    const int outoff = phase ? CH : 0;
    if (phase) {
      __syncthreads();                    // all rs writes done
      rs[tid] = SCALE / rs[tid];          // rs -> fw table
      __syncthreads();
    }
#pragma unroll 1
    for (int q=0;q<4;++q) {
      const int m0 = q*64 + wid*16;
      bfv8 af[3];
#pragma unroll
      for (int ks=0;ks<3;++ks)
        af[ks] = *(const bfv8*)(msrc + (size_t)(m0+l15)*CH + ks*32 + lg*8);
      float rsum[4]={0.f,0.f,0.f,0.f};
      // ---- scores in 2 chunks of 128 columns ----
#pragma unroll
      for (int c2=0;c2<2;++c2){
        f32x4 acc[8];
#pragma unroll
        for (int nt=0;nt<8;++nt) acc[nt]=(f32x4){0.f,0.f,0.f,0.f};
#pragma unroll
        for (int ks=0;ks<3;++ks)
#pragma unroll
          for (int nt=0;nt<8;++nt)
            acc[nt] = MFMA16(af[ks],
                *(const bfv8*)(nsrc + (size_t)(c2*128+nt*16+l15)*CH + ks*32+lg*8), acc[nt]);
        if (phase==0){
#pragma unroll
          for (int nt=0;nt<8;++nt)
#pragma unroll
            for (int r=0;r<4;++r){
              float e=__expf(acc[nt][r]); rsum[r]+=e;
              aq[(wid*16+lg*4+r)*264 + c2*128+nt*16+l15] = f2b(e);
            }
        } else {
#pragma unroll
          for (int nt=0;nt<8;++nt){
            float fwv = rs[c2*128+nt*16+l15];
#pragma unroll
            for (int r=0;r<4;++r)
              aq[(wid*16+lg*4+r)*264 + c2*128+nt*16+l15] = f2b(__expf(acc[nt][r])*fwv);
          }
        }
      }
      float sc[4];
      if (phase==0){
#pragma unroll
        for (int off=1; off<16; off<<=1)
#pragma unroll
          for (int r=0;r<4;++r) rsum[r] += __shfl_xor(rsum[r], off, 64);
        if (l15==0){
#pragma unroll
          for (int r=0;r<4;++r) rs[m0 + lg*4 + r] = rsum[r];
        }
#pragma unroll
        for (int r=0;r<4;++r) sc[r] = SCALE / rsum[r];
      } else {
#pragma unroll
        for (int r=0;r<4;++r) sc[r] = 1.f;
      }
      // ---- apply GEMM: own 16 rows x k=256 x 96c ----
      f32x4 o[6];
#pragma unroll
      for (int nt=0;nt<6;++nt) o[nt]=(f32x4){0.f,0.f,0.f,0.f};
#pragma unroll
      for (int ks=0;ks<8;++ks) {
        bfv8 aa = *(const bfv8*)(aq + (wid*16+l15)*264 + ks*32 + lg*8);
#pragma unroll
        for (int nt=0;nt<6;++nt)
          o[nt] = MFMA16(aa,
              *(const bfv8*)(vt + (size_t)(nt*16+l15)*WID + ks*32+lg*8), o[nt]);
      }
      // ---- stage into own aq rows (wave-private; done reading them) ----
#pragma unroll
      for (int nt=0;nt<6;++nt)
#pragma unroll
        for (int r=0;r<4;++r)
          aq[(wid*16+lg*4+r)*264 + nt*16+l15] = f2b(o[nt][r]*sc[r]);
      // ---- coalesced global write: 16 rows x 96 bf16 (192B runs) ----
      const size_t pbase = (size_t)bh*WID + m0;
#pragma unroll
      for (int i=0;i<3;++i){
        int u = lane + 64*i;          // 0..191
        int gr = u/12, sg = u%12;
        *(bfv8*)(Fout + (pbase+gr)*192 + outoff + sg*8) =
            *(const bfv8*)(aq + (wid*16+gr)*264 + sg*8);
      }
    }
  }
}

// ---------------- K_wprep: fold lp2/beta/rp2/gamma/down into Wcat[96][384] + b'[96] ----------------
__global__ __launch_bounds__(256) void k_wprep(
    const float* __restrict__ L, const float* __restrict__ lb,
    const float* __restrict__ R, const float* __restrict__ rb,
    const float* __restrict__ D, const float* __restrict__ db,
    const float* __restrict__ beta, const float* __restrict__ gamma,
    bf* __restrict__ Wcat, float* __restrict__ bv)
{
  const int o = blockIdx.x;
  const int tid = threadIdx.x;
  for (int k = tid; k < 384; k += 256){
    float v;
    if (k < 192) v = D[o*192 + k];
    else if (k < 288){
      int c = k - 192; float s = 0.f;
      for (int m=0;m<96;++m) s += D[o*192+m]*beta[m]*L[m*96+c];
      v = s;
    } else {
      int c = k - 288; float s = 0.f;
      for (int m=0;m<96;++m) s += D[o*192+96+m]*gamma[m]*R[m*96+c];
      v = s;
    }
    Wcat[o*384+k] = f2b(v);
  }
  if (tid == 0){
    float s = db[o];
    for (int m=0;m<96;++m) s += D[o*192+m]*beta[m]*lb[m] + D[o*192+96+m]*gamma[m]*rb[m];
    bv[o] = s;
  }
}

// ---------------- K3: out = [x_l | x_r | F1 | F2] @ Wcat + b' ----------------
__global__ __launch_bounds__(256) void k_fuse(
    const float* __restrict__ I1, const float* __restrict__ I2,
    const bf* F, const bf* __restrict__ Wcat, const float* __restrict__ bv,
    float* OUT)
{
  extern __shared__ bf fls[];   // [128][200]
  const int tid=threadIdx.x, lane=tid&63, wv=tid>>6;
  const int l15=lane&15, lg=lane>>4;
  const int half = wv&1, pair = wv>>1;
  const size_t p0 = (size_t)blockIdx.x * 128;

  {
    const int row = tid>>1, seg = (tid&1)*96;
    const bf* fsrc = F + (p0+row)*192 + seg;
    bf* ldst = fls + row*200 + seg;
#pragma unroll
    for (int i=0;i<12;++i) *(bfv8*)(ldst + i*8) = *(const bfv8*)(fsrc + i*8);
  }

  bfv8 wf[12][3];
  float bias[3];
#pragma unroll
  for (int j=0;j<3;++j){
    int c = (half*3+j)*16 + l15;
    bias[j] = bv[c];
#pragma unroll
    for (int kb=0;kb<12;++kb)
      wf[kb][j] = *(const bfv8*)(Wcat + (size_t)c*384 + kb*32 + lg*8);
  }
  __syncthreads();

#pragma unroll
  for (int i=0;i<4;++i){
    const int mloc = (pair*4+i)*16;
    const size_t m0 = p0 + mloc;
    bfv8 a[12];
    const float* x1 = I1 + (m0+l15)*CH + lg*8;
    const float* x2 = I2 + (m0+l15)*CH + lg*8;
    const bf* fp = fls + (mloc+l15)*200 + lg*8;
#pragma unroll
    for (int ks=0;ks<3;++ks){
      a[ks]   = ld_cvt8(x1 + ks*32);
      a[3+ks] = ld_cvt8(x2 + ks*32);
      a[6+ks] = *(const bfv8*)(fp + ks*32);
      a[9+ks] = *(const bfv8*)(fp + 96 + ks*32);
    }
    f32x4 acc[3];
#pragma unroll
    for (int j=0;j<3;++j) acc[j]=(f32x4){bias[j],bias[j],bias[j],bias[j]};
#pragma unroll
    for (int kb=0;kb<12;++kb)
#pragma unroll
      for (int j=0;j<3;++j)
        acc[j] = MFMA16(a[kb], wf[kb][j], acc[j]);
#pragma unroll
    for (int j=0;j<3;++j){
      int c = (half*3+j)*16 + l15;
#pragma unroll
      for (int r=0;r<4;++r)
        OUT[(m0+lg*4+r)*CH + c] = acc[j][r];
    }
  }
}

extern "C" void kernel_launch(void* const* d_in, const int* in_sizes, int n_in,
                              void* d_out, int out_size, void* d_ws, size_t ws_size,
                              hipStream_t stream)
{
  (void)in_sizes; (void)n_in; (void)out_size; (void)ws_size;
  const float* I1 = (const float*)d_in[0];
  const float* I2 = (const float*)d_in[1];
  const float* se1_w = (const float*)d_in[4];
  const float* se1_b = (const float*)d_in[5];
  const float* se1_dw= (const float*)d_in[6];
  const float* se1_db= (const float*)d_in[7];
  const float* se2_w = (const float*)d_in[8];
  const float* se2_b = (const float*)d_in[9];
  const float* se2_dw= (const float*)d_in[10];
  const float* se2_db= (const float*)d_in[11];
  const float* lp1_w = (const float*)d_in[12];
  const float* lp1_b = (const float*)d_in[13];
  const float* lp1_dw= (const float*)d_in[14];
  const float* lp1_db= (const float*)d_in[15];
  const float* rp1_w = (const float*)d_in[16];
  const float* rp1_b = (const float*)d_in[17];
  const float* rp1_dw= (const float*)d_in[18];
  const float* rp1_db= (const float*)d_in[19];
  const float* lp2_w = (const float*)d_in[20];
  const float* lp2_b = (const float*)d_in[21];
  const float* rp2_w = (const float*)d_in[22];
  const float* rp2_b = (const float*)d_in[23];
  const float* down_w= (const float*)d_in[24];
  const float* down_b= (const float*)d_in[25];
  const float* beta  = (const float*)d_in[26];
  const float* gamma = (const float*)d_in[27];
  float* OUT = (float*)d_out;
  bf* Fbuf = (bf*)d_out;

  const size_t FIELD = (size_t)NB * HGT * WID * CH;
  bf* Ql = (bf*)d_ws;
  bf* Qr = Ql + FIELD;
  bf* Vl = Qr + FIELD;
  bf* Vr = Vl + FIELD;
  bf* Wcat = Vr + FIELD;
  float* bv = (float*)(Wcat + 96*384);

  dim3 blk(256,1,1);
  k_wprep<<<dim3(96,1,1), blk, 0, stream>>>(lp2_w, lp2_b, rp2_w, rp2_b,
        down_w, down_b, beta, gamma, Wcat, bv);
  k_proj2<<<dim3(4,128,NB), blk, HROWS*TSTR*2, stream>>>(I1,
        se1_w, se1_b, se1_dw, se1_db, Ql,
        lp1_w, lp1_b, lp1_dw, lp1_db, Vl);
  k_proj2<<<dim3(4,128,NB), blk, HROWS*TSTR*2, stream>>>(I2,
        se2_w, se2_b, se2_dw, se2_db, Qr,
        rp1_w, rp1_b, rp1_dw, rp1_db, Vr);
  k_vt<<<dim3(NB*HGT,2,1), blk, 0, stream>>>(Vl, Vr);
  k_attn<<<dim3(NB*HGT,1,1), blk, 64*264*2 + 256*4, stream>>>(Ql, Qr, Vl, Vr, Fbuf);
  k_fuse<<<dim3(4096,1,1), blk, 128*200*2, stream>>>(I1, I2, Fbuf, Wcat, bv, OUT);
}

// Round 6
// 1660.347 us; speedup vs baseline: 1.8355x; 1.8355x over previous
//
#include <hip/hip_runtime.h>
#include <hip/hip_bf16.h>
#include <stdint.h>

typedef __bf16 bf;
typedef __bf16 bfv8 __attribute__((ext_vector_type(8)));
typedef __bf16 bfv4 __attribute__((ext_vector_type(4)));
typedef float  f32x4 __attribute__((ext_vector_type(4)));

#define MFMA16(a,b,c) __builtin_amdgcn_mfma_f32_16x16x32_bf16((a),(b),(c),0,0,0)

#define CH  96
#define WID 256
#define HGT 256
#define NB  8
#define SCALE 0.1020620726159658f   // 96^-0.5

__device__ __forceinline__ float b2f(bf x){ return (float)x; }
__device__ __forceinline__ bf   f2b(float x){ return (bf)x; }

__device__ __forceinline__ bfv8 ld_cvt8(const float* __restrict__ p){
  f32x4 a = *(const f32x4*)p;
  f32x4 b = *(const f32x4*)(p + 4);
  bfv8 r;
  r[0]=f2b(a[0]); r[1]=f2b(a[1]); r[2]=f2b(a[2]); r[3]=f2b(a[3]);
  r[4]=f2b(b[0]); r[5]=f2b(b[1]); r[6]=f2b(b[2]); r[7]=f2b(b[3]);
  return r;
}

// ---------------- K1: dual fused conv1x1 (MFMA) + depthwise 3x3 ----------------
#define TW 64
#define TH 2
#define HC 66
#define HROWS 264
#define TSTR 96

__global__ __launch_bounds__(256) void k_proj2(
    const float* __restrict__ X,
    const float* __restrict__ W1a, const float* __restrict__ B1a,
    const float* __restrict__ WDa, const float* __restrict__ BDa, bf* __restrict__ Oa,
    const float* __restrict__ W1b, const float* __restrict__ B1b,
    const float* __restrict__ WDb, const float* __restrict__ BDb, bf* __restrict__ Ob)
{
  extern __shared__ bf tile[];  // [264][96] = 50,688 B
  const int tid=threadIdx.x, lane=tid&63, wid=tid>>6;
  const int l15=lane&15, lg=lane>>4;
  const int gx=blockIdx.x*TW, gy=blockIdx.y*TH, b=blockIdx.z;
  const size_t ibase=(size_t)b*(HGT*WID)*CH;

  bfv8 af[5][3];
#pragma unroll
  for (int i=0;i<5;++i){
    int mt=wid+i*4;
    int p=mt*16+l15;
    int hr=p/HC, hcc=p%HC;
    int y=gy-1+hr, x=gx-1+hcc;
    bool inb=(mt<17)&&(p<HROWS)&&(y>=0)&&(y<HGT)&&(x>=0)&&(x<WID);
#pragma unroll
    for (int ks=0;ks<3;++ks){
      bfv8 v={0,0,0,0,0,0,0,0};
      if (inb) v=ld_cvt8(X+ibase+((size_t)y*WID+x)*CH+ks*32+lg*8);
      af[i][ks]=v;
    }
  }

#pragma unroll 1
  for (int pass=0; pass<2; ++pass){
    const float* W1 = pass?W1b:W1a;
    const float* B1 = pass?B1b:B1a;
    const float* WD = pass?WDb:WDa;
    const float* BD = pass?BDb:BDa;
    bf* O = pass?Ob:Oa;
    if (pass) __syncthreads();
    {
      bfv8 wf[6][3];
      float bias[6];
#pragma unroll
      for (int nt=0;nt<6;++nt){
        bias[nt]=B1[nt*16+l15];
#pragma unroll
        for (int ks=0;ks<3;++ks) wf[nt][ks]=ld_cvt8(W1+(nt*16+l15)*CH+ks*32+lg*8);
      }
#pragma unroll
      for (int i=0;i<5;++i){
        int mt=wid+i*4;
        if (mt>=17) continue;
        f32x4 acc[6];
#pragma unroll
        for (int nt=0;nt<6;++nt) acc[nt]=(f32x4){bias[nt],bias[nt],bias[nt],bias[nt]};
#pragma unroll
        for (int ks=0;ks<3;++ks)
#pragma unroll
          for (int nt=0;nt<6;++nt) acc[nt]=MFMA16(af[i][ks],wf[nt][ks],acc[nt]);
        int prow=mt*16+lg*4;
#pragma unroll
        for (int r=0;r<4;++r){
          int pp=prow+r;
          if (pp<HROWS){
            int hr2=pp/HC,hc2=pp%HC;
            int yy=gy-1+hr2, xx=gx-1+hc2;
            bool ib=(yy>=0)&&(yy<HGT)&&(xx>=0)&&(xx<WID);
#pragma unroll
            for (int nt=0;nt<6;++nt) tile[pp*TSTR+nt*16+l15]=f2b(ib?acc[nt][r]:0.f);
          }
        }
      }
    }
    __syncthreads();
    if (tid<252){
      int g=tid%12, pi0=tid/12;
      float w9[8][9], bb[8];
#pragma unroll
      for (int j=0;j<8;++j){
#pragma unroll
        for (int t=0;t<9;++t) w9[j][t]=WD[(g*8+j)*9+t];
        bb[j]=BD[g*8+j];
      }
      for (int pi=pi0; pi<TW*TH; pi+=21){
        int oy=pi/TW, ox=pi%TW;
        int y=gy+oy;
        float acc[8];
#pragma unroll
        for (int j=0;j<8;++j) acc[j]=bb[j];
#pragma unroll
        for (int dy=0;dy<3;++dy)
#pragma unroll
          for (int dx=0;dx<3;++dx){
            bfv8 v8=*(const bfv8*)(tile+((oy+dy)*HC+(ox+dx))*TSTR+g*8);
#pragma unroll
            for (int j=0;j<8;++j) acc[j]+=w9[j][dy*3+dx]*b2f(v8[j]);
          }
        bf* dst=O+ibase+((size_t)y*WID+gx+ox)*CH+g*8;
        bfv8 st;
#pragma unroll
        for (int j=0;j<8;++j) st[j]=f2b(acc[j]);
        *(bfv8*)dst=st;
      }
    }
  }
}

// ---------------- K_attn: fused scores+softmax+apply, LDS-resident V^T ----------------
// One block per (b,h). LDS: vt[96][264] (V^T staged+transposed from row-major V),
// aq = per-wave [16][104] P-bounce / F-stage, rs[256] rowsums->fw. Total 65,024 B.
// phase 0: S = Ql Qr^T in 4x64-col chunks; aq <- exp(S) unscaled; o += aq @ vt chunk;
//          final o *= SCALE/rowsum (deferred scale). rowsums -> rs.
// phase 1: S^T = Qr Ql^T chunks; aq <- exp(S^T)*fw[col]; o += aq @ vt chunk.
__global__ __launch_bounds__(256) void k_attn(
    const bf* __restrict__ Ql, const bf* __restrict__ Qr,
    const bf* __restrict__ Vl, const bf* __restrict__ Vr,
    bf* __restrict__ Fout)
{
  extern __shared__ char sm[];
  bf* vt = (bf*)sm;                          // [96][264] = 50,688 B
  bf* aq = (bf*)(sm + 96*264*2);             // 4 x [16][104] = 13,312 B
  float* rs = (float*)(sm + 96*264*2 + 4*16*104*2);  // [256] = 1,024 B
  const int tid=threadIdx.x, lane=tid&63, wid=tid>>6;
  const int l15=lane&15, lg=lane>>4;
  bf* aqw = aq + wid*(16*104);
  const int bh = blockIdx.x;
  const size_t qoff = (size_t)bh * (WID*CH);

#pragma unroll 1
  for (int phase=0; phase<2; ++phase) {
    const bf* msrc = phase ? Qr+qoff : Ql+qoff;
    const bf* nsrc = phase ? Ql+qoff : Qr+qoff;
    const bf* V    = (phase ? Vl : Vr) + qoff;
    const int outoff = phase ? CH : 0;
    if (phase) {
      __syncthreads();               // phase-0 vt/aq reads + rs writes done
      rs[tid] = SCALE / rs[tid];     // rs -> fw table (own entry)
    }
    { // stage V^T: thread t reads V row v=t (96 ch), writes vt[c][t]
      const bfv8* src = (const bfv8*)(V + (size_t)tid*CH);
#pragma unroll
      for (int i=0;i<12;++i){
        bfv8 v8 = src[i];
#pragma unroll
        for (int j=0;j<8;++j) vt[(i*8+j)*264 + tid] = v8[j];
      }
    }
    __syncthreads();                 // vt ready (+ fw published)

#pragma unroll 1
    for (int q=0;q<4;++q){
      const int m0 = q*64 + wid*16;
      bfv8 af[3];
#pragma unroll
      for (int ks=0;ks<3;++ks)
        af[ks] = *(const bfv8*)(msrc + (size_t)(m0+l15)*CH + ks*32 + lg*8);
      f32x4 o[6];
#pragma unroll
      for (int nt=0;nt<6;++nt) o[nt]=(f32x4){0.f,0.f,0.f,0.f};
      float rsum[4]={0.f,0.f,0.f,0.f};

#pragma unroll 1
      for (int c4=0;c4<4;++c4){
        // ---- scores chunk: 16 m-rows x 64 v-cols ----
        f32x4 acc[4];
#pragma unroll
        for (int nt=0;nt<4;++nt) acc[nt]=(f32x4){0.f,0.f,0.f,0.f};
#pragma unroll
        for (int ks=0;ks<3;++ks)
#pragma unroll
          for (int nt=0;nt<4;++nt)
            acc[nt]=MFMA16(af[ks],
              *(const bfv8*)(nsrc + (size_t)(c4*64+nt*16+l15)*CH + ks*32+lg*8), acc[nt]);
        // ---- exp -> wave-private aq ----
        if (phase==0){
#pragma unroll
          for (int nt=0;nt<4;++nt)
#pragma unroll
            for (int r=0;r<4;++r){
              float e=__expf(acc[nt][r]); rsum[r]+=e;
              aqw[(lg*4+r)*104 + nt*16+l15] = f2b(e);
            }
        } else {
#pragma unroll
          for (int nt=0;nt<4;++nt){
            float fwv = rs[c4*64+nt*16+l15];
#pragma unroll
            for (int r=0;r<4;++r)
              aqw[(lg*4+r)*104 + nt*16+l15] = f2b(__expf(acc[nt][r])*fwv);
          }
        }
        // ---- PV partial over this 64-wide k chunk (vt from LDS) ----
#pragma unroll
        for (int ks=0;ks<2;++ks){
          bfv8 aa = *(const bfv8*)(aqw + l15*104 + ks*32 + lg*8);
#pragma unroll
          for (int nt=0;nt<6;++nt)
            o[nt]=MFMA16(aa,
              *(const bfv8*)(vt + (nt*16+l15)*264 + c4*64 + ks*32 + lg*8), o[nt]);
        }
      }
      // ---- deferred row scale ----
      float sc[4];
      if (phase==0){
#pragma unroll
        for (int off=1; off<16; off<<=1)
#pragma unroll
          for (int r=0;r<4;++r) rsum[r]+=__shfl_xor(rsum[r],off,64);
        if (l15==0){
#pragma unroll
          for (int r=0;r<4;++r) rs[m0+lg*4+r]=rsum[r];
        }
#pragma unroll
        for (int r=0;r<4;++r) sc[r]=SCALE/rsum[r];
      } else {
#pragma unroll
        for (int r=0;r<4;++r) sc[r]=1.f;
      }
      // ---- stage F tile into own aq rows, then coalesced 16B writes ----
#pragma unroll
      for (int nt=0;nt<6;++nt)
#pragma unroll
        for (int r=0;r<4;++r)
          aqw[(lg*4+r)*104 + nt*16+l15] = f2b(o[nt][r]*sc[r]);
      const size_t pbase=(size_t)bh*WID + m0;
#pragma unroll
      for (int i=0;i<3;++i){
        int u=lane+64*i; int gr=u/12, sg=u%12;
        *(bfv8*)(Fout + (pbase+gr)*192 + outoff + sg*8)
          = *(const bfv8*)(aqw + gr*104 + sg*8);
      }
    }
  }
}

// ---------------- K_wprep: fold lp2/beta/rp2/gamma/down into Wcat[96][384] + b'[96] ----------------
__global__ __launch_bounds__(256) void k_wprep(
    const float* __restrict__ L, const float* __restrict__ lb,
    const float* __restrict__ R, const float* __restrict__ rb,
    const float* __restrict__ D, const float* __restrict__ db,
    const float* __restrict__ beta, const float* __restrict__ gamma,
    bf* __restrict__ Wcat, float* __restrict__ bv)
{
  const int o = blockIdx.x;
  const int tid = threadIdx.x;
  for (int k = tid; k < 384; k += 256){
    float v;
    if (k < 192) v = D[o*192 + k];
    else if (k < 288){
      int c = k - 192; float s = 0.f;
      for (int m=0;m<96;++m) s += D[o*192+m]*beta[m]*L[m*96+c];
      v = s;
    } else {
      int c = k - 288; float s = 0.f;
      for (int m=0;m<96;++m) s += D[o*192+96+m]*gamma[m]*R[m*96+c];
      v = s;
    }
    Wcat[o*384+k] = f2b(v);
  }
  if (tid == 0){
    float s = db[o];
    for (int m=0;m<96;++m) s += D[o*192+m]*beta[m]*lb[m] + D[o*192+96+m]*gamma[m]*rb[m];
    bv[o] = s;
  }
}

// ---------------- K3: out = [x_l | x_r | F1 | F2] @ Wcat + b' ----------------
__global__ __launch_bounds__(256) void k_fuse(
    const float* __restrict__ I1, const float* __restrict__ I2,
    const bf* F, const bf* __restrict__ Wcat, const float* __restrict__ bv,
    float* OUT)
{
  extern __shared__ bf fls[];   // [128][200]
  const int tid=threadIdx.x, lane=tid&63, wv=tid>>6;
  const int l15=lane&15, lg=lane>>4;
  const int half = wv&1, pair = wv>>1;
  const size_t p0 = (size_t)blockIdx.x * 128;

  {
    const int row = tid>>1, seg = (tid&1)*96;
    const bf* fsrc = F + (p0+row)*192 + seg;
    bf* ldst = fls + row*200 + seg;
#pragma unroll
    for (int i=0;i<12;++i) *(bfv8*)(ldst + i*8) = *(const bfv8*)(fsrc + i*8);
  }

  bfv8 wf[12][3];
  float bias[3];
#pragma unroll
  for (int j=0;j<3;++j){
    int c = (half*3+j)*16 + l15;
    bias[j] = bv[c];
#pragma unroll
    for (int kb=0;kb<12;++kb)
      wf[kb][j] = *(const bfv8*)(Wcat + (size_t)c*384 + kb*32 + lg*8);
  }
  __syncthreads();

#pragma unroll
  for (int i=0;i<4;++i){
    const int mloc = (pair*4+i)*16;
    const size_t m0 = p0 + mloc;
    bfv8 a[12];
    const float* x1 = I1 + (m0+l15)*CH + lg*8;
    const float* x2 = I2 + (m0+l15)*CH + lg*8;
    const bf* fp = fls + (mloc+l15)*200 + lg*8;
#pragma unroll
    for (int ks=0;ks<3;++ks){
      a[ks]   = ld_cvt8(x1 + ks*32);
      a[3+ks] = ld_cvt8(x2 + ks*32);
      a[6+ks] = *(const bfv8*)(fp + ks*32);
      a[9+ks] = *(const bfv8*)(fp + 96 + ks*32);
    }
    f32x4 acc[3];
#pragma unroll
    for (int j=0;j<3;++j) acc[j]=(f32x4){bias[j],bias[j],bias[j],bias[j]};
#pragma unroll
    for (int kb=0;kb<12;++kb)
#pragma unroll
      for (int j=0;j<3;++j)
        acc[j] = MFMA16(a[kb], wf[kb][j], acc[j]);
#pragma unroll
    for (int j=0;j<3;++j){
      int c = (half*3+j)*16 + l15;
#pragma unroll
      for (int r=0;r<4;++r)
        OUT[(m0+lg*4+r)*CH + c] = acc[j][r];
    }
  }
}

extern "C" void kernel_launch(void* const* d_in, const int* in_sizes, int n_in,
                              void* d_out, int out_size, void* d_ws, size_t ws_size,
                              hipStream_t stream)
{
  (void)in_sizes; (void)n_in; (void)out_size; (void)ws_size;
  const float* I1 = (const float*)d_in[0];
  const float* I2 = (const float*)d_in[1];
  const float* se1_w = (const float*)d_in[4];
  const float* se1_b = (const float*)d_in[5];
  const float* se1_dw= (const float*)d_in[6];
  const float* se1_db= (const float*)d_in[7];
  const float* se2_w = (const float*)d_in[8];
  const float* se2_b = (const float*)d_in[9];
  const float* se2_dw= (const float*)d_in[10];
  const float* se2_db= (const float*)d_in[11];
  const float* lp1_w = (const float*)d_in[12];
  const float* lp1_b = (const float*)d_in[13];
  const float* lp1_dw= (const float*)d_in[14];
  const float* lp1_db= (const float*)d_in[15];
  const float* rp1_w = (const float*)d_in[16];
  const float* rp1_b = (const float*)d_in[17];
  const float* rp1_dw= (const float*)d_in[18];
  const float* rp1_db= (const float*)d_in[19];
  const float* lp2_w = (const float*)d_in[20];
  const float* lp2_b = (const float*)d_in[21];
  const float* rp2_w = (const float*)d_in[22];
  const float* rp2_b = (const float*)d_in[23];
  const float* down_w= (const float*)d_in[24];
  const float* down_b= (const float*)d_in[25];
  const float* beta  = (const float*)d_in[26];
  const float* gamma = (const float*)d_in[27];
  float* OUT = (float*)d_out;
  bf* Fbuf = (bf*)d_out;

  const size_t FIELD = (size_t)NB * HGT * WID * CH;
  bf* Ql = (bf*)d_ws;
  bf* Qr = Ql + FIELD;
  bf* Vl = Qr + FIELD;
  bf* Vr = Vl + FIELD;
  bf* Wcat = Vr + FIELD;
  float* bv = (float*)(Wcat + 96*384);

  dim3 blk(256,1,1);
  k_wprep<<<dim3(96,1,1), blk, 0, stream>>>(lp2_w, lp2_b, rp2_w, rp2_b,
        down_w, down_b, beta, gamma, Wcat, bv);
  k_proj2<<<dim3(4,128,NB), blk, HROWS*TSTR*2, stream>>>(I1,
        se1_w, se1_b, se1_dw, se1_db, Ql,
        lp1_w, lp1_b, lp1_dw, lp1_db, Vl);
  k_proj2<<<dim3(4,128,NB), blk, HROWS*TSTR*2, stream>>>(I2,
        se2_w, se2_b, se2_dw, se2_db, Qr,
        rp1_w, rp1_b, rp1_dw, rp1_db, Vr);
  k_attn<<<dim3(NB*HGT,1,1), blk, 96*264*2 + 4*16*104*2 + 256*4, stream>>>(
        Ql, Qr, Vl, Vr, Fbuf);
  k_fuse<<<dim3(4096,1,1), blk, 128*200*2, stream>>>(I1, I2, Fbuf, Wcat, bv, OUT);
}

// Round 7
// 1348.920 us; speedup vs baseline: 2.2593x; 1.2309x over previous
//
#include <hip/hip_runtime.h>
#include <hip/hip_bf16.h>
#include <stdint.h>

typedef __bf16 bf;
typedef __bf16 bfv8 __attribute__((ext_vector_type(8)));
typedef __bf16 bfv4 __attribute__((ext_vector_type(4)));
typedef float  f32x4 __attribute__((ext_vector_type(4)));

#define MFMA16(a,b,c) __builtin_amdgcn_mfma_f32_16x16x32_bf16((a),(b),(c),0,0,0)

#define CH  96
#define WID 256
#define HGT 256
#define NB  8
#define SCALE 0.1020620726159658f   // 96^-0.5

__device__ __forceinline__ float b2f(bf x){ return (float)x; }
__device__ __forceinline__ bf   f2b(float x){ return (bf)x; }

__device__ __forceinline__ bfv8 ld_cvt8(const float* __restrict__ p){
  f32x4 a = *(const f32x4*)p;
  f32x4 b = *(const f32x4*)(p + 4);
  bfv8 r;
  r[0]=f2b(a[0]); r[1]=f2b(a[1]); r[2]=f2b(a[2]); r[3]=f2b(a[3]);
  r[4]=f2b(b[0]); r[5]=f2b(b[1]); r[6]=f2b(b[2]); r[7]=f2b(b[3]);
  return r;
}

// ---------------- K1: dual fused conv1x1 (MFMA) + depthwise 3x3 ----------------
#define TW 64
#define TH 2
#define HC 66
#define HROWS 264
#define TSTR 96

__global__ __launch_bounds__(256) void k_proj2(
    const float* __restrict__ X,
    const float* __restrict__ W1a, const float* __restrict__ B1a,
    const float* __restrict__ WDa, const float* __restrict__ BDa, bf* __restrict__ Oa,
    const float* __restrict__ W1b, const float* __restrict__ B1b,
    const float* __restrict__ WDb, const float* __restrict__ BDb, bf* __restrict__ Ob)
{
  extern __shared__ bf tile[];  // [264][96] = 50,688 B
  const int tid=threadIdx.x, lane=tid&63, wid=tid>>6;
  const int l15=lane&15, lg=lane>>4;
  const int gx=blockIdx.x*TW, gy=blockIdx.y*TH, b=blockIdx.z;
  const size_t ibase=(size_t)b*(HGT*WID)*CH;

  bfv8 af[5][3];
#pragma unroll
  for (int i=0;i<5;++i){
    int mt=wid+i*4;
    int p=mt*16+l15;
    int hr=p/HC, hcc=p%HC;
    int y=gy-1+hr, x=gx-1+hcc;
    bool inb=(mt<17)&&(p<HROWS)&&(y>=0)&&(y<HGT)&&(x>=0)&&(x<WID);
#pragma unroll
    for (int ks=0;ks<3;++ks){
      bfv8 v={0,0,0,0,0,0,0,0};
      if (inb) v=ld_cvt8(X+ibase+((size_t)y*WID+x)*CH+ks*32+lg*8);
      af[i][ks]=v;
    }
  }

#pragma unroll 1
  for (int pass=0; pass<2; ++pass){
    const float* W1 = pass?W1b:W1a;
    const float* B1 = pass?B1b:B1a;
    const float* WD = pass?WDb:WDa;
    const float* BD = pass?BDb:BDa;
    bf* O = pass?Ob:Oa;
    if (pass) __syncthreads();
    {
      bfv8 wf[6][3];
      float bias[6];
#pragma unroll
      for (int nt=0;nt<6;++nt){
        bias[nt]=B1[nt*16+l15];
#pragma unroll
        for (int ks=0;ks<3;++ks) wf[nt][ks]=ld_cvt8(W1+(nt*16+l15)*CH+ks*32+lg*8);
      }
#pragma unroll
      for (int i=0;i<5;++i){
        int mt=wid+i*4;
        if (mt>=17) continue;
        f32x4 acc[6];
#pragma unroll
        for (int nt=0;nt<6;++nt) acc[nt]=(f32x4){bias[nt],bias[nt],bias[nt],bias[nt]};
#pragma unroll
        for (int ks=0;ks<3;++ks)
#pragma unroll
          for (int nt=0;nt<6;++nt) acc[nt]=MFMA16(af[i][ks],wf[nt][ks],acc[nt]);
        int prow=mt*16+lg*4;
#pragma unroll
        for (int r=0;r<4;++r){
          int pp=prow+r;
          if (pp<HROWS){
            int hr2=pp/HC,hc2=pp%HC;
            int yy=gy-1+hr2, xx=gx-1+hc2;
            bool ib=(yy>=0)&&(yy<HGT)&&(xx>=0)&&(xx<WID);
#pragma unroll
            for (int nt=0;nt<6;++nt) tile[pp*TSTR+nt*16+l15]=f2b(ib?acc[nt][r]:0.f);
          }
        }
      }
    }
    __syncthreads();
    if (tid<252){
      int g=tid%12, pi0=tid/12;
      float w9[8][9], bb[8];
#pragma unroll
      for (int j=0;j<8;++j){
#pragma unroll
        for (int t=0;t<9;++t) w9[j][t]=WD[(g*8+j)*9+t];
        bb[j]=BD[g*8+j];
      }
      for (int pi=pi0; pi<TW*TH; pi+=21){
        int oy=pi/TW, ox=pi%TW;
        int y=gy+oy;
        float acc[8];
#pragma unroll
        for (int j=0;j<8;++j) acc[j]=bb[j];
#pragma unroll
        for (int dy=0;dy<3;++dy)
#pragma unroll
          for (int dx=0;dx<3;++dx){
            bfv8 v8=*(const bfv8*)(tile+((oy+dy)*HC+(ox+dx))*TSTR+g*8);
#pragma unroll
            for (int j=0;j<8;++j) acc[j]+=w9[j][dy*3+dx]*b2f(v8[j]);
          }
        bf* dst=O+ibase+((size_t)y*WID+gx+ox)*CH+g*8;
        bfv8 st;
#pragma unroll
        for (int j=0;j<8;++j) st[j]=f2b(acc[j]);
        *(bfv8*)dst=st;
      }
    }
  }
}

// ---------------- K_attn v3: fused scores+softmax+apply, register-cached B-frags ----------------
// One block per (b,h). LDS: vt[96][264] (V^T), aq = per-wave [16][104], rs[256]. 65,024 B.
// Loop order: phase -> qp(2) -> c4(4) -> q01(2): nb B-frags loaded once per c4 and
// reused by both q01 row-groups (24 MFMAs per load set); two independent
// score->exp->bounce->PV chains in flight per wave for latency hiding.
__global__ __launch_bounds__(256) void k_attn(
    const bf* __restrict__ Ql, const bf* __restrict__ Qr,
    const bf* __restrict__ Vl, const bf* __restrict__ Vr,
    bf* __restrict__ Fout)
{
  extern __shared__ char sm[];
  bf* vt = (bf*)sm;                          // [96][264] = 50,688 B
  bf* aq = (bf*)(sm + 96*264*2);             // 4 x [16][104] = 13,312 B
  float* rs = (float*)(sm + 96*264*2 + 4*16*104*2);  // [256] = 1,024 B
  const int tid=threadIdx.x, lane=tid&63, wid=tid>>6;
  const int l15=lane&15, lg=lane>>4;
  bf* aqw = aq + wid*(16*104);
  const int bh = blockIdx.x;
  const size_t qoff = (size_t)bh * (WID*CH);

#pragma unroll 1
  for (int phase=0; phase<2; ++phase) {
    const bf* msrc = phase ? Qr+qoff : Ql+qoff;
    const bf* nsrc = phase ? Ql+qoff : Qr+qoff;
    const bf* V    = (phase ? Vl : Vr) + qoff;
    const int outoff = phase ? CH : 0;
    if (phase) {
      __syncthreads();               // phase-0 vt/aq reads + rs writes done
      rs[tid] = SCALE / rs[tid];     // rs -> fw table (own entry)
    }
    { // stage V^T: thread t reads V row v=t (96 ch), writes vt[c][t]
      const bfv8* src = (const bfv8*)(V + (size_t)tid*CH);
#pragma unroll
      for (int i=0;i<12;++i){
        bfv8 v8 = src[i];
#pragma unroll
        for (int j=0;j<8;++j) vt[(i*8+j)*264 + tid] = v8[j];
      }
    }
    __syncthreads();                 // vt ready (+ fw published)

#pragma unroll 1
    for (int qp=0; qp<2; ++qp){
      // A-frags for both row-groups of this pair (held across c4)
      bfv8 af2[2][3];
#pragma unroll
      for (int q01=0;q01<2;++q01){
        const int m0 = (qp*2+q01)*64 + wid*16;
#pragma unroll
        for (int ks=0;ks<3;++ks)
          af2[q01][ks] = *(const bfv8*)(msrc + (size_t)(m0+l15)*CH + ks*32 + lg*8);
      }
      f32x4 o[2][6];
#pragma unroll
      for (int q01=0;q01<2;++q01)
#pragma unroll
        for (int nt=0;nt<6;++nt) o[q01][nt]=(f32x4){0.f,0.f,0.f,0.f};
      float rsum[2][4]={{0.f,0.f,0.f,0.f},{0.f,0.f,0.f,0.f}};

#pragma unroll 1
      for (int c4=0;c4<4;++c4){
        // B-frags for this 64-col chunk: loaded ONCE, reused by both q01
        bfv8 nb[4][3];
#pragma unroll
        for (int nt=0;nt<4;++nt)
#pragma unroll
          for (int ks=0;ks<3;++ks)
            nb[nt][ks] = *(const bfv8*)(nsrc + (size_t)(c4*64+nt*16+l15)*CH + ks*32+lg*8);
        float fwv[4];
        if (phase){
#pragma unroll
          for (int nt=0;nt<4;++nt) fwv[nt] = rs[c4*64+nt*16+l15];
        }
#pragma unroll
        for (int q01=0;q01<2;++q01){
          // ---- scores chunk: 16 m-rows x 64 v-cols (register operands only) ----
          f32x4 acc[4];
#pragma unroll
          for (int nt=0;nt<4;++nt) acc[nt]=(f32x4){0.f,0.f,0.f,0.f};
#pragma unroll
          for (int ks=0;ks<3;++ks)
#pragma unroll
            for (int nt=0;nt<4;++nt)
              acc[nt]=MFMA16(af2[q01][ks], nb[nt][ks], acc[nt]);
          // ---- exp -> wave-private aq ----
          if (phase==0){
#pragma unroll
            for (int nt=0;nt<4;++nt)
#pragma unroll
              for (int r=0;r<4;++r){
                float e=__expf(acc[nt][r]); rsum[q01][r]+=e;
                aqw[(lg*4+r)*104 + nt*16+l15] = f2b(e);
              }
          } else {
#pragma unroll
            for (int nt=0;nt<4;++nt){
#pragma unroll
              for (int r=0;r<4;++r)
                aqw[(lg*4+r)*104 + nt*16+l15] = f2b(__expf(acc[nt][r])*fwv[nt]);
            }
          }
          // ---- PV partial over this 64-wide k chunk (vt from LDS) ----
#pragma unroll
          for (int ks=0;ks<2;++ks){
            bfv8 aa = *(const bfv8*)(aqw + l15*104 + ks*32 + lg*8);
#pragma unroll
            for (int nt=0;nt<6;++nt)
              o[q01][nt]=MFMA16(aa,
                *(const bfv8*)(vt + (nt*16+l15)*264 + c4*64 + ks*32 + lg*8), o[q01][nt]);
          }
        }
      }
      // ---- finalize both row-groups: deferred scale, stage, coalesced store ----
#pragma unroll
      for (int q01=0;q01<2;++q01){
        const int m0 = (qp*2+q01)*64 + wid*16;
        float sc[4];
        if (phase==0){
#pragma unroll
          for (int off=1; off<16; off<<=1)
#pragma unroll
            for (int r=0;r<4;++r) rsum[q01][r]+=__shfl_xor(rsum[q01][r],off,64);
          if (l15==0){
#pragma unroll
            for (int r=0;r<4;++r) rs[m0+lg*4+r]=rsum[q01][r];
          }
#pragma unroll
          for (int r=0;r<4;++r) sc[r]=SCALE/rsum[q01][r];
        } else {
#pragma unroll
          for (int r=0;r<4;++r) sc[r]=1.f;
        }
#pragma unroll
        for (int nt=0;nt<6;++nt)
#pragma unroll
          for (int r=0;r<4;++r)
            aqw[(lg*4+r)*104 + nt*16+l15] = f2b(o[q01][nt][r]*sc[r]);
        const size_t pbase=(size_t)bh*WID + m0;
#pragma unroll
        for (int i=0;i<3;++i){
          int u=lane+64*i; int gr=u/12, sg=u%12;
          *(bfv8*)(Fout + (pbase+gr)*192 + outoff + sg*8)
            = *(const bfv8*)(aqw + gr*104 + sg*8);
        }
      }
    }
  }
}

// ---------------- K_wprep: fold lp2/beta/rp2/gamma/down into Wcat[96][384] + b'[96] ----------------
__global__ __launch_bounds__(256) void k_wprep(
    const float* __restrict__ L, const float* __restrict__ lb,
    const float* __restrict__ R, const float* __restrict__ rb,
    const float* __restrict__ D, const float* __restrict__ db,
    const float* __restrict__ beta, const float* __restrict__ gamma,
    bf* __restrict__ Wcat, float* __restrict__ bv)
{
  const int o = blockIdx.x;
  const int tid = threadIdx.x;
  for (int k = tid; k < 384; k += 256){
    float v;
    if (k < 192) v = D[o*192 + k];
    else if (k < 288){
      int c = k - 192; float s = 0.f;
      for (int m=0;m<96;++m) s += D[o*192+m]*beta[m]*L[m*96+c];
      v = s;
    } else {
      int c = k - 288; float s = 0.f;
      for (int m=0;m<96;++m) s += D[o*192+96+m]*gamma[m]*R[m*96+c];
      v = s;
    }
    Wcat[o*384+k] = f2b(v);
  }
  if (tid == 0){
    float s = db[o];
    for (int m=0;m<96;++m) s += D[o*192+m]*beta[m]*lb[m] + D[o*192+96+m]*gamma[m]*rb[m];
    bv[o] = s;
  }
}

// ---------------- K3: out = [x_l | x_r | F1 | F2] @ Wcat + b' ----------------
__global__ __launch_bounds__(256) void k_fuse(
    const float* __restrict__ I1, const float* __restrict__ I2,
    const bf* F, const bf* __restrict__ Wcat, const float* __restrict__ bv,
    float* OUT)
{
  extern __shared__ bf fls[];   // [128][200]
  const int tid=threadIdx.x, lane=tid&63, wv=tid>>6;
  const int l15=lane&15, lg=lane>>4;
  const int half = wv&1, pair = wv>>1;
  const size_t p0 = (size_t)blockIdx.x * 128;

  {
    const int row = tid>>1, seg = (tid&1)*96;
    const bf* fsrc = F + (p0+row)*192 + seg;
    bf* ldst = fls + row*200 + seg;
#pragma unroll
    for (int i=0;i<12;++i) *(bfv8*)(ldst + i*8) = *(const bfv8*)(fsrc + i*8);
  }

  bfv8 wf[12][3];
  float bias[3];
#pragma unroll
  for (int j=0;j<3;++j){
    int c = (half*3+j)*16 + l15;
    bias[j] = bv[c];
#pragma unroll
    for (int kb=0;kb<12;++kb)
      wf[kb][j] = *(const bfv8*)(Wcat + (size_t)c*384 + kb*32 + lg*8);
  }
  __syncthreads();

#pragma unroll
  for (int i=0;i<4;++i){
    const int mloc = (pair*4+i)*16;
    const size_t m0 = p0 + mloc;
    bfv8 a[12];
    const float* x1 = I1 + (m0+l15)*CH + lg*8;
    const float* x2 = I2 + (m0+l15)*CH + lg*8;
    const bf* fp = fls + (mloc+l15)*200 + lg*8;
#pragma unroll
    for (int ks=0;ks<3;++ks){
      a[ks]   = ld_cvt8(x1 + ks*32);
      a[3+ks] = ld_cvt8(x2 + ks*32);
      a[6+ks] = *(const bfv8*)(fp + ks*32);
      a[9+ks] = *(const bfv8*)(fp + 96 + ks*32);
    }
    f32x4 acc[3];
#pragma unroll
    for (int j=0;j<3;++j) acc[j]=(f32x4){bias[j],bias[j],bias[j],bias[j]};
#pragma unroll
    for (int kb=0;kb<12;++kb)
#pragma unroll
      for (int j=0;j<3;++j)
        acc[j] = MFMA16(a[kb], wf[kb][j], acc[j]);
#pragma unroll
    for (int j=0;j<3;++j){
      int c = (half*3+j)*16 + l15;
#pragma unroll
      for (int r=0;r<4;++r)
        OUT[(m0+lg*4+r)*CH + c] = acc[j][r];
    }
  }
}

extern "C" void kernel_launch(void* const* d_in, const int* in_sizes, int n_in,
                              void* d_out, int out_size, void* d_ws, size_t ws_size,
                              hipStream_t stream)
{
  (void)in_sizes; (void)n_in; (void)out_size; (void)ws_size;
  const float* I1 = (const float*)d_in[0];
  const float* I2 = (const float*)d_in[1];
  const float* se1_w = (const float*)d_in[4];
  const float* se1_b = (const float*)d_in[5];
  const float* se1_dw= (const float*)d_in[6];
  const float* se1_db= (const float*)d_in[7];
  const float* se2_w = (const float*)d_in[8];
  const float* se2_b = (const float*)d_in[9];
  const float* se2_dw= (const float*)d_in[10];
  const float* se2_db= (const float*)d_in[11];
  const float* lp1_w = (const float*)d_in[12];
  const float* lp1_b = (const float*)d_in[13];
  const float* lp1_dw= (const float*)d_in[14];
  const float* lp1_db= (const float*)d_in[15];
  const float* rp1_w = (const float*)d_in[16];
  const float* rp1_b = (const float*)d_in[17];
  const float* rp1_dw= (const float*)d_in[18];
  const float* rp1_db= (const float*)d_in[19];
  const float* lp2_w = (const float*)d_in[20];
  const float* lp2_b = (const float*)d_in[21];
  const float* rp2_w = (const float*)d_in[22];
  const float* rp2_b = (const float*)d_in[23];
  const float* down_w= (const float*)d_in[24];
  const float* down_b= (const float*)d_in[25];
  const float* beta  = (const float*)d_in[26];
  const float* gamma = (const float*)d_in[27];
  float* OUT = (float*)d_out;
  bf* Fbuf = (bf*)d_out;

  const size_t FIELD = (size_t)NB * HGT * WID * CH;
  bf* Ql = (bf*)d_ws;
  bf* Qr = Ql + FIELD;
  bf* Vl = Qr + FIELD;
  bf* Vr = Vl + FIELD;
  bf* Wcat = Vr + FIELD;
  float* bv = (float*)(Wcat + 96*384);

  dim3 blk(256,1,1);
  k_wprep<<<dim3(96,1,1), blk, 0, stream>>>(lp2_w, lp2_b, rp2_w, rp2_b,
        down_w, down_b, beta, gamma, Wcat, bv);
  k_proj2<<<dim3(4,128,NB), blk, HROWS*TSTR*2, stream>>>(I1,
        se1_w, se1_b, se1_dw, se1_db, Ql,
        lp1_w, lp1_b, lp1_dw, lp1_db, Vl);
  k_proj2<<<dim3(4,128,NB), blk, HROWS*TSTR*2, stream>>>(I2,
        se2_w, se2_b, se2_dw, se2_db, Qr,
        rp1_w, rp1_b, rp1_dw, rp1_db, Vr);
  k_attn<<<dim3(NB*HGT,1,1), blk, 96*264*2 + 4*16*104*2 + 256*4, stream>>>(
        Ql, Qr, Vl, Vr, Fbuf);
  k_fuse<<<dim3(4096,1,1), blk, 128*200*2, stream>>>(I1, I2, Fbuf, Wcat, bv, OUT);
}

// Round 8
// 1076.369 us; speedup vs baseline: 2.8314x; 1.2532x over previous
//
#include <hip/hip_runtime.h>
#include <hip/hip_bf16.h>
#include <stdint.h>

typedef __bf16 bf;
typedef __bf16 bfv8 __attribute__((ext_vector_type(8)));
typedef __bf16 bfv4 __attribute__((ext_vector_type(4)));
typedef float  f32x4 __attribute__((ext_vector_type(4)));

#define MFMA16(a,b,c) __builtin_amdgcn_mfma_f32_16x16x32_bf16((a),(b),(c),0,0,0)

#define CH  96
#define WID 256
#define HGT 256
#define NB  8
#define SCALE 0.1020620726159658f   // 96^-0.5

__device__ __forceinline__ float b2f(bf x){ return (float)x; }
__device__ __forceinline__ bf   f2b(float x){ return (bf)x; }

__device__ __forceinline__ bfv8 ld_cvt8(const float* __restrict__ p){
  f32x4 a = *(const f32x4*)p;
  f32x4 b = *(const f32x4*)(p + 4);
  bfv8 r;
  r[0]=f2b(a[0]); r[1]=f2b(a[1]); r[2]=f2b(a[2]); r[3]=f2b(a[3]);
  r[4]=f2b(b[0]); r[5]=f2b(b[1]); r[6]=f2b(b[2]); r[7]=f2b(b[3]);
  return r;
}

// ---------------- K_c1x1: pure conv1x1 GEMM, two weight sets per block ----------------
// 256 px/block, 4 waves: wave w -> set (w&1), m-tile half (w>>1). No LDS, no barriers.
// A-frags direct from global f32 (both sets' waves hit the same rows -> L2 dedup).
__global__ __launch_bounds__(256) void k_c1x1(
    const float* __restrict__ X,
    const float* __restrict__ Wa, const float* __restrict__ Ba,
    const float* __restrict__ Wb, const float* __restrict__ Bb,
    bf* __restrict__ Ca, bf* __restrict__ Cb)
{
  const int tid=threadIdx.x, lane=tid&63, wv=tid>>6;
  const int l15=lane&15, lg=lane>>4;
  const int set = wv&1, th = wv>>1;
  const float* W1 = set ? Wb : Wa;
  const float* B1 = set ? Bb : Ba;
  bf* C = set ? Cb : Ca;
  const size_t p0 = (size_t)blockIdx.x * 256;

  bfv8 wf[6][3];
  float bias[6];
#pragma unroll
  for (int nt=0;nt<6;++nt){
    bias[nt] = B1[nt*16+l15];
#pragma unroll
    for (int ks=0;ks<3;++ks)
      wf[nt][ks] = ld_cvt8(W1 + (nt*16+l15)*CH + ks*32 + lg*8);
  }

#pragma unroll 1
  for (int i=0;i<8;++i){
    const int m0 = (th*8+i)*16;
    bfv8 af[3];
#pragma unroll
    for (int ks=0;ks<3;++ks)
      af[ks] = ld_cvt8(X + (p0+m0+l15)*CH + ks*32 + lg*8);
    f32x4 acc[6];
#pragma unroll
    for (int nt=0;nt<6;++nt) acc[nt]=(f32x4){bias[nt],bias[nt],bias[nt],bias[nt]};
#pragma unroll
    for (int ks=0;ks<3;++ks)
#pragma unroll
      for (int nt=0;nt<6;++nt)
        acc[nt] = MFMA16(af[ks], wf[nt][ks], acc[nt]);
#pragma unroll
    for (int nt=0;nt<6;++nt){
      int c = nt*16 + l15;
#pragma unroll
      for (int r=0;r<4;++r)
        C[(p0+m0+lg*4+r)*CH + c] = f2b(acc[nt][r]);
    }
  }
}

// ---------------- K_dw: depthwise 3x3 from global (bf16), register sliding window ----------------
// Thread = (octet g of 12) x (slot of 20: 4 x-runs x 5 y-rows). Run = 16 px along x.
// 54 x 16B loads per 16 outputs; no LDS, no barriers; L2 absorbs y-halo overlap.
__global__ __launch_bounds__(256) void k_dw(
    const bf* __restrict__ C0, const bf* __restrict__ C1,
    const float* __restrict__ WD0, const float* __restrict__ BD0,
    const float* __restrict__ WD1, const float* __restrict__ BD1,
    bf* __restrict__ O0, bf* __restrict__ O1)
{
  const int tid = threadIdx.x;
  if (tid >= 240) return;
  const int g = tid % 12, slot = tid / 12;   // slot 0..19
  const int yrow = slot >> 2, xrun = slot & 3;
  const int b = blockIdx.z >> 1, s = blockIdx.z & 1;
  const bf* C = s ? C1 : C0;
  const float* WD = s ? WD1 : WD0;
  const float* BD = s ? BD1 : BD0;
  bf* O = s ? O1 : O0;
  const int x0 = blockIdx.x*64 + xrun*16;
  const int y  = blockIdx.y*5 + yrow;
  if (y >= HGT) return;
  const size_t ib = (size_t)b * (HGT*WID) * CH;

  float wv[9][8], bb[8];
#pragma unroll
  for (int j=0;j<8;++j){
    bb[j] = BD[g*8+j];
#pragma unroll
    for (int t=0;t<9;++t) wv[t][j] = WD[(g*8+j)*9 + t];
  }

  const bf* r0 = C + ib + ((size_t)(y-1)*WID)*CH + g*8;
  const bf* r1 = C + ib + ((size_t)(y  )*WID)*CH + g*8;
  const bf* r2 = C + ib + ((size_t)(y+1)*WID)*CH + g*8;
  const bool v0 = (y > 0), v2 = (y+1 < HGT);
  const bfv8 Z = {0,0,0,0,0,0,0,0};

  bfv8 w00,w01,w02, w10,w11,w12, w20,w21,w22;
  { // col x0-1
    bool vx = (x0 > 0);
    size_t o = (size_t)(x0-1)*CH;
    w00 = (v0&&vx) ? *(const bfv8*)(r0+o) : Z;
    w10 = vx       ? *(const bfv8*)(r1+o) : Z;
    w20 = (v2&&vx) ? *(const bfv8*)(r2+o) : Z;
  }
  { // col x0
    size_t o = (size_t)x0*CH;
    w01 = v0 ? *(const bfv8*)(r0+o) : Z;
    w11 =      *(const bfv8*)(r1+o);
    w21 = v2 ? *(const bfv8*)(r2+o) : Z;
  }
#pragma unroll
  for (int xi=0; xi<16; ++xi){
    const int xn = x0 + xi + 1;
    const bool vx = (xn < WID);
    const size_t o = (size_t)xn*CH;
    w02 = (v0&&vx) ? *(const bfv8*)(r0+o) : Z;
    w12 = vx       ? *(const bfv8*)(r1+o) : Z;
    w22 = (v2&&vx) ? *(const bfv8*)(r2+o) : Z;
    float acc[8];
#pragma unroll
    for (int j=0;j<8;++j) acc[j] = bb[j];
#pragma unroll
    for (int j=0;j<8;++j){
      acc[j] += wv[0][j]*b2f(w00[j]);
      acc[j] += wv[1][j]*b2f(w01[j]);
      acc[j] += wv[2][j]*b2f(w02[j]);
      acc[j] += wv[3][j]*b2f(w10[j]);
      acc[j] += wv[4][j]*b2f(w11[j]);
      acc[j] += wv[5][j]*b2f(w12[j]);
      acc[j] += wv[6][j]*b2f(w20[j]);
      acc[j] += wv[7][j]*b2f(w21[j]);
      acc[j] += wv[8][j]*b2f(w22[j]);
    }
    bfv8 st;
#pragma unroll
    for (int j=0;j<8;++j) st[j] = f2b(acc[j]);
    *(bfv8*)(O + ib + ((size_t)y*WID + x0 + xi)*CH + g*8) = st;
    w00=w01; w01=w02;
    w10=w11; w11=w12;
    w20=w21; w21=w22;
  }
}

// ---------------- K_attn v3: fused scores+softmax+apply, register-cached B-frags ----------------
__global__ __launch_bounds__(256) void k_attn(
    const bf* __restrict__ Ql, const bf* __restrict__ Qr,
    const bf* __restrict__ Vl, const bf* __restrict__ Vr,
    bf* __restrict__ Fout)
{
  extern __shared__ char sm[];
  bf* vt = (bf*)sm;                          // [96][264] = 50,688 B
  bf* aq = (bf*)(sm + 96*264*2);             // 4 x [16][104] = 13,312 B
  float* rs = (float*)(sm + 96*264*2 + 4*16*104*2);  // [256] = 1,024 B
  const int tid=threadIdx.x, lane=tid&63, wid=tid>>6;
  const int l15=lane&15, lg=lane>>4;
  bf* aqw = aq + wid*(16*104);
  const int bh = blockIdx.x;
  const size_t qoff = (size_t)bh * (WID*CH);

#pragma unroll 1
  for (int phase=0; phase<2; ++phase) {
    const bf* msrc = phase ? Qr+qoff : Ql+qoff;
    const bf* nsrc = phase ? Ql+qoff : Qr+qoff;
    const bf* V    = (phase ? Vl : Vr) + qoff;
    const int outoff = phase ? CH : 0;
    if (phase) {
      __syncthreads();               // phase-0 vt/aq reads + rs writes done
      rs[tid] = SCALE / rs[tid];     // rs -> fw table (own entry)
    }
    { // stage V^T: thread t reads V row v=t (96 ch), writes vt[c][t]
      const bfv8* src = (const bfv8*)(V + (size_t)tid*CH);
#pragma unroll
      for (int i=0;i<12;++i){
        bfv8 v8 = src[i];
#pragma unroll
        for (int j=0;j<8;++j) vt[(i*8+j)*264 + tid] = v8[j];
      }
    }
    __syncthreads();                 // vt ready (+ fw published)

#pragma unroll 1
    for (int qp=0; qp<2; ++qp){
      bfv8 af2[2][3];
#pragma unroll
      for (int q01=0;q01<2;++q01){
        const int m0 = (qp*2+q01)*64 + wid*16;
#pragma unroll
        for (int ks=0;ks<3;++ks)
          af2[q01][ks] = *(const bfv8*)(msrc + (size_t)(m0+l15)*CH + ks*32 + lg*8);
      }
      f32x4 o[2][6];
#pragma unroll
      for (int q01=0;q01<2;++q01)
#pragma unroll
        for (int nt=0;nt<6;++nt) o[q01][nt]=(f32x4){0.f,0.f,0.f,0.f};
      float rsum[2][4]={{0.f,0.f,0.f,0.f},{0.f,0.f,0.f,0.f}};

#pragma unroll 1
      for (int c4=0;c4<4;++c4){
        bfv8 nb[4][3];
#pragma unroll
        for (int nt=0;nt<4;++nt)
#pragma unroll
          for (int ks=0;ks<3;++ks)
            nb[nt][ks] = *(const bfv8*)(nsrc + (size_t)(c4*64+nt*16+l15)*CH + ks*32+lg*8);
        float fwv[4];
        if (phase){
#pragma unroll
          for (int nt=0;nt<4;++nt) fwv[nt] = rs[c4*64+nt*16+l15];
        }
#pragma unroll
        for (int q01=0;q01<2;++q01){
          f32x4 acc[4];
#pragma unroll
          for (int nt=0;nt<4;++nt) acc[nt]=(f32x4){0.f,0.f,0.f,0.f};
#pragma unroll
          for (int ks=0;ks<3;++ks)
#pragma unroll
            for (int nt=0;nt<4;++nt)
              acc[nt]=MFMA16(af2[q01][ks], nb[nt][ks], acc[nt]);
          if (phase==0){
#pragma unroll
            for (int nt=0;nt<4;++nt)
#pragma unroll
              for (int r=0;r<4;++r){
                float e=__expf(acc[nt][r]); rsum[q01][r]+=e;
                aqw[(lg*4+r)*104 + nt*16+l15] = f2b(e);
              }
          } else {
#pragma unroll
            for (int nt=0;nt<4;++nt){
#pragma unroll
              for (int r=0;r<4;++r)
                aqw[(lg*4+r)*104 + nt*16+l15] = f2b(__expf(acc[nt][r])*fwv[nt]);
            }
          }
#pragma unroll
          for (int ks=0;ks<2;++ks){
            bfv8 aa = *(const bfv8*)(aqw + l15*104 + ks*32 + lg*8);
#pragma unroll
            for (int nt=0;nt<6;++nt)
              o[q01][nt]=MFMA16(aa,
                *(const bfv8*)(vt + (nt*16+l15)*264 + c4*64 + ks*32 + lg*8), o[q01][nt]);
          }
        }
      }
#pragma unroll
      for (int q01=0;q01<2;++q01){
        const int m0 = (qp*2+q01)*64 + wid*16;
        float sc[4];
        if (phase==0){
#pragma unroll
          for (int off=1; off<16; off<<=1)
#pragma unroll
            for (int r=0;r<4;++r) rsum[q01][r]+=__shfl_xor(rsum[q01][r],off,64);
          if (l15==0){
#pragma unroll
            for (int r=0;r<4;++r) rs[m0+lg*4+r]=rsum[q01][r];
          }
#pragma unroll
          for (int r=0;r<4;++r) sc[r]=SCALE/rsum[q01][r];
        } else {
#pragma unroll
          for (int r=0;r<4;++r) sc[r]=1.f;
        }
#pragma unroll
        for (int nt=0;nt<6;++nt)
#pragma unroll
          for (int r=0;r<4;++r)
            aqw[(lg*4+r)*104 + nt*16+l15] = f2b(o[q01][nt][r]*sc[r]);
        const size_t pbase=(size_t)bh*WID + m0;
#pragma unroll
        for (int i=0;i<3;++i){
          int u=lane+64*i; int gr=u/12, sg=u%12;
          *(bfv8*)(Fout + (pbase+gr)*192 + outoff + sg*8)
            = *(const bfv8*)(aqw + gr*104 + sg*8);
        }
      }
    }
  }
}

// ---------------- K_wprep: fold lp2/beta/rp2/gamma/down into Wcat[96][384] + b'[96] ----------------
__global__ __launch_bounds__(256) void k_wprep(
    const float* __restrict__ L, const float* __restrict__ lb,
    const float* __restrict__ R, const float* __restrict__ rb,
    const float* __restrict__ D, const float* __restrict__ db,
    const float* __restrict__ beta, const float* __restrict__ gamma,
    bf* __restrict__ Wcat, float* __restrict__ bv)
{
  const int o = blockIdx.x;
  const int tid = threadIdx.x;
  for (int k = tid; k < 384; k += 256){
    float v;
    if (k < 192) v = D[o*192 + k];
    else if (k < 288){
      int c = k - 192; float s = 0.f;
      for (int m=0;m<96;++m) s += D[o*192+m]*beta[m]*L[m*96+c];
      v = s;
    } else {
      int c = k - 288; float s = 0.f;
      for (int m=0;m<96;++m) s += D[o*192+96+m]*gamma[m]*R[m*96+c];
      v = s;
    }
    Wcat[o*384+k] = f2b(v);
  }
  if (tid == 0){
    float s = db[o];
    for (int m=0;m<96;++m) s += D[o*192+m]*beta[m]*lb[m] + D[o*192+96+m]*gamma[m]*rb[m];
    bv[o] = s;
  }
}

// ---------------- K3: out = [x_l | x_r | F1 | F2] @ Wcat + b' ----------------
__global__ __launch_bounds__(256) void k_fuse(
    const float* __restrict__ I1, const float* __restrict__ I2,
    const bf* F, const bf* __restrict__ Wcat, const float* __restrict__ bv,
    float* OUT)
{
  extern __shared__ bf fls[];   // [128][200]
  const int tid=threadIdx.x, lane=tid&63, wv=tid>>6;
  const int l15=lane&15, lg=lane>>4;
  const int half = wv&1, pair = wv>>1;
  const size_t p0 = (size_t)blockIdx.x * 128;

  {
    const int row = tid>>1, seg = (tid&1)*96;
    const bf* fsrc = F + (p0+row)*192 + seg;
    bf* ldst = fls + row*200 + seg;
#pragma unroll
    for (int i=0;i<12;++i) *(bfv8*)(ldst + i*8) = *(const bfv8*)(fsrc + i*8);
  }

  bfv8 wf[12][3];
  float bias[3];
#pragma unroll
  for (int j=0;j<3;++j){
    int c = (half*3+j)*16 + l15;
    bias[j] = bv[c];
#pragma unroll
    for (int kb=0;kb<12;++kb)
      wf[kb][j] = *(const bfv8*)(Wcat + (size_t)c*384 + kb*32 + lg*8);
  }
  __syncthreads();

#pragma unroll
  for (int i=0;i<4;++i){
    const int mloc = (pair*4+i)*16;
    const size_t m0 = p0 + mloc;
    bfv8 a[12];
    const float* x1 = I1 + (m0+l15)*CH + lg*8;
    const float* x2 = I2 + (m0+l15)*CH + lg*8;
    const bf* fp = fls + (mloc+l15)*200 + lg*8;
#pragma unroll
    for (int ks=0;ks<3;++ks){
      a[ks]   = ld_cvt8(x1 + ks*32);
      a[3+ks] = ld_cvt8(x2 + ks*32);
      a[6+ks] = *(const bfv8*)(fp + ks*32);
      a[9+ks] = *(const bfv8*)(fp + 96 + ks*32);
    }
    f32x4 acc[3];
#pragma unroll
    for (int j=0;j<3;++j) acc[j]=(f32x4){bias[j],bias[j],bias[j],bias[j]};
#pragma unroll
    for (int kb=0;kb<12;++kb)
#pragma unroll
      for (int j=0;j<3;++j)
        acc[j] = MFMA16(a[kb], wf[kb][j], acc[j]);
#pragma unroll
    for (int j=0;j<3;++j){
      int c = (half*3+j)*16 + l15;
#pragma unroll
      for (int r=0;r<4;++r)
        OUT[(m0+lg*4+r)*CH + c] = acc[j][r];
    }
  }
}

extern "C" void kernel_launch(void* const* d_in, const int* in_sizes, int n_in,
                              void* d_out, int out_size, void* d_ws, size_t ws_size,
                              hipStream_t stream)
{
  (void)in_sizes; (void)n_in; (void)out_size; (void)ws_size;
  const float* I1 = (const float*)d_in[0];
  const float* I2 = (const float*)d_in[1];
  const float* se1_w = (const float*)d_in[4];
  const float* se1_b = (const float*)d_in[5];
  const float* se1_dw= (const float*)d_in[6];
  const float* se1_db= (const float*)d_in[7];
  const float* se2_w = (const float*)d_in[8];
  const float* se2_b = (const float*)d_in[9];
  const float* se2_dw= (const float*)d_in[10];
  const float* se2_db= (const float*)d_in[11];
  const float* lp1_w = (const float*)d_in[12];
  const float* lp1_b = (const float*)d_in[13];
  const float* lp1_dw= (const float*)d_in[14];
  const float* lp1_db= (const float*)d_in[15];
  const float* rp1_w = (const float*)d_in[16];
  const float* rp1_b = (const float*)d_in[17];
  const float* rp1_dw= (const float*)d_in[18];
  const float* rp1_db= (const float*)d_in[19];
  const float* lp2_w = (const float*)d_in[20];
  const float* lp2_b = (const float*)d_in[21];
  const float* rp2_w = (const float*)d_in[22];
  const float* rp2_b = (const float*)d_in[23];
  const float* down_w= (const float*)d_in[24];
  const float* down_b= (const float*)d_in[25];
  const float* beta  = (const float*)d_in[26];
  const float* gamma = (const float*)d_in[27];
  float* OUT = (float*)d_out;
  bf* Fbuf = (bf*)d_out;

  const size_t FIELD = (size_t)NB * HGT * WID * CH;   // 50,331,648 elems
  bf* Ql = (bf*)d_ws;
  bf* Qr = Ql + FIELD;
  bf* Vl = Qr + FIELD;
  bf* Vr = Vl + FIELD;
  bf* Wcat = Vr + FIELD;
  float* bv = (float*)(Wcat + 96*384);
  // conv1x1 intermediates aliased into d_out (2*FIELD bf16 == out_size f32 bytes,
  // dead before k_attn overwrites d_out with F)
  bf* Cq = (bf*)d_out;
  bf* Cv = Cq + FIELD;

  dim3 blk(256,1,1);
  k_wprep<<<dim3(96,1,1), blk, 0, stream>>>(lp2_w, lp2_b, rp2_w, rp2_b,
        down_w, down_b, beta, gamma, Wcat, bv);
  // left image: conv1x1 (se1, lp1) -> Cq,Cv ; then depthwise -> Ql, Vl
  k_c1x1<<<dim3(2048,1,1), blk, 0, stream>>>(I1, se1_w, se1_b, lp1_w, lp1_b, Cq, Cv);
  k_dw  <<<dim3(4,52,16),  blk, 0, stream>>>(Cq, Cv, se1_dw, se1_db, lp1_dw, lp1_db, Ql, Vl);
  // right image
  k_c1x1<<<dim3(2048,1,1), blk, 0, stream>>>(I2, se2_w, se2_b, rp1_w, rp1_b, Cq, Cv);
  k_dw  <<<dim3(4,52,16),  blk, 0, stream>>>(Cq, Cv, se2_dw, se2_db, rp1_dw, rp1_db, Qr, Vr);

  k_attn<<<dim3(NB*HGT,1,1), blk, 96*264*2 + 4*16*104*2 + 256*4, stream>>>(
        Ql, Qr, Vl, Vr, Fbuf);
  k_fuse<<<dim3(4096,1,1), blk, 128*200*2, stream>>>(I1, I2, Fbuf, Wcat, bv, OUT);
}

// Round 9
// 1030.959 us; speedup vs baseline: 2.9561x; 1.0440x over previous
//
#include <hip/hip_runtime.h>
#include <hip/hip_bf16.h>
#include <stdint.h>

typedef __bf16 bf;
typedef __bf16 bfv8 __attribute__((ext_vector_type(8)));
typedef __bf16 bfv4 __attribute__((ext_vector_type(4)));
typedef float  f32x4 __attribute__((ext_vector_type(4)));

#define MFMA16(a,b,c) __builtin_amdgcn_mfma_f32_16x16x32_bf16((a),(b),(c),0,0,0)

#define CH  96
#define WID 256
#define HGT 256
#define NB  8
#define SCALE 0.1020620726159658f   // 96^-0.5

__device__ __forceinline__ float b2f(bf x){ return (float)x; }
__device__ __forceinline__ bf   f2b(float x){ return (bf)x; }

__device__ __forceinline__ bfv8 ld_cvt8(const float* __restrict__ p){
  f32x4 a = *(const f32x4*)p;
  f32x4 b = *(const f32x4*)(p + 4);
  bfv8 r;
  r[0]=f2b(a[0]); r[1]=f2b(a[1]); r[2]=f2b(a[2]); r[3]=f2b(a[3]);
  r[4]=f2b(b[0]); r[5]=f2b(b[1]); r[6]=f2b(b[2]); r[7]=f2b(b[3]);
  return r;
}
__device__ __forceinline__ bfv4 pack4(float a,float b,float c,float d){
  bfv4 r; r[0]=f2b(a); r[1]=f2b(b); r[2]=f2b(c); r[3]=f2b(d); return r;
}

// ---------------- K_c1x1: conv1x1 GEMM, weights-as-A (packed stores), prefetch ----------------
// 256 px/block, 4 waves: wave w -> set (w&1), m-tile half (w>>1). No LDS, no barriers.
// Output layout per lane: 4 consecutive c_out for one pixel -> bfv4 8B stores.
__global__ __launch_bounds__(256) void k_c1x1(
    const float* __restrict__ X,
    const float* __restrict__ Wa, const float* __restrict__ Ba,
    const float* __restrict__ Wb, const float* __restrict__ Bb,
    bf* __restrict__ Ca, bf* __restrict__ Cb)
{
  const int tid=threadIdx.x, lane=tid&63, wv=tid>>6;
  const int l15=lane&15, lg=lane>>4;
  const int set = wv&1, th = wv>>1;
  const float* W1 = set ? Wb : Wa;
  const float* B1 = set ? Bb : Ba;
  bf* C = set ? Cb : Ca;
  const size_t p0 = (size_t)blockIdx.x * 256;

  bfv8 wf[6][3];          // A-frags: lane l15 = c_out row
  f32x4 bias4[6];
#pragma unroll
  for (int nt=0;nt<6;++nt){
    bias4[nt] = *(const f32x4*)(B1 + nt*16 + lg*4);
#pragma unroll
    for (int ks=0;ks<3;++ks)
      wf[nt][ks] = ld_cvt8(W1 + (nt*16+l15)*CH + ks*32 + lg*8);
  }

  bfv8 af[3], afn[3];
#pragma unroll
  for (int ks=0;ks<3;++ks)
    af[ks] = ld_cvt8(X + (p0 + th*8*16 + l15)*CH + ks*32 + lg*8);
#pragma unroll 1
  for (int i=0;i<8;++i){
    const int m0 = (th*8+i)*16;
    if (i<7){
#pragma unroll
      for (int ks=0;ks<3;++ks)
        afn[ks] = ld_cvt8(X + (p0+m0+16+l15)*CH + ks*32 + lg*8);
    }
    f32x4 acc[6];
#pragma unroll
    for (int nt=0;nt<6;++nt) acc[nt]=bias4[nt];
#pragma unroll
    for (int ks=0;ks<3;++ks)
#pragma unroll
      for (int nt=0;nt<6;++nt)
        acc[nt] = MFMA16(wf[nt][ks], af[ks], acc[nt]);   // A=W, B=X
#pragma unroll
    for (int nt=0;nt<6;++nt)
      *(bfv4*)(C + (p0+m0+l15)*CH + nt*16 + lg*4)
        = pack4(acc[nt][0],acc[nt][1],acc[nt][2],acc[nt][3]);
#pragma unroll
    for (int ks=0;ks<3;++ks) af[ks]=afn[ks];
  }
}

// ---------------- K_dw: depthwise 3x3, software-pipelined sliding window ----------------
__global__ __launch_bounds__(256) void k_dw(
    const bf* __restrict__ C0, const bf* __restrict__ C1,
    const float* __restrict__ WD0, const float* __restrict__ BD0,
    const float* __restrict__ WD1, const float* __restrict__ BD1,
    bf* __restrict__ O0, bf* __restrict__ O1)
{
  const int tid = threadIdx.x;
  if (tid >= 240) return;
  const int g = tid % 12, slot = tid / 12;   // slot 0..19
  const int yrow = slot >> 2, xrun = slot & 3;
  const int b = blockIdx.z >> 1, s = blockIdx.z & 1;
  const bf* C = s ? C1 : C0;
  const float* WD = s ? WD1 : WD0;
  const float* BD = s ? BD1 : BD0;
  bf* O = s ? O1 : O0;
  const int x0 = blockIdx.x*64 + xrun*16;
  const int y  = blockIdx.y*5 + yrow;
  if (y >= HGT) return;
  const size_t ib = (size_t)b * (HGT*WID) * CH;

  float wv[9][8], bb[8];
#pragma unroll
  for (int j=0;j<8;++j){
    bb[j] = BD[g*8+j];
#pragma unroll
    for (int t=0;t<9;++t) wv[t][j] = WD[(g*8+j)*9 + t];
  }

  const bf* r0 = C + ib + ((size_t)(y-1)*WID)*CH + g*8;
  const bf* r1 = C + ib + ((size_t)(y  )*WID)*CH + g*8;
  const bf* r2 = C + ib + ((size_t)(y+1)*WID)*CH + g*8;
  const bool v0 = (y > 0), v2 = (y+1 < HGT);
  const bfv8 Z = {0,0,0,0,0,0,0,0};

  bfv8 w00,w01,w02, w10,w11,w12, w20,w21,w22, n0,n1,n2;
  { // col x0-1
    bool vx = (x0 > 0);
    size_t o = (size_t)(x0-1)*CH;
    w00 = (v0&&vx) ? *(const bfv8*)(r0+o) : Z;
    w10 = vx       ? *(const bfv8*)(r1+o) : Z;
    w20 = (v2&&vx) ? *(const bfv8*)(r2+o) : Z;
  }
  { // col x0
    size_t o = (size_t)x0*CH;
    w01 = v0 ? *(const bfv8*)(r0+o) : Z;
    w11 =      *(const bfv8*)(r1+o);
    w21 = v2 ? *(const bfv8*)(r2+o) : Z;
  }
  { // col x0+1 (prefetch)
    int xn = x0+1; bool vx = (xn < WID);
    size_t o = (size_t)xn*CH;
    n0 = (v0&&vx) ? *(const bfv8*)(r0+o) : Z;
    n1 = vx       ? *(const bfv8*)(r1+o) : Z;
    n2 = (v2&&vx) ? *(const bfv8*)(r2+o) : Z;
  }
#pragma unroll
  for (int xi=0; xi<16; ++xi){
    w02 = n0; w12 = n1; w22 = n2;
    { // issue NEXT column's loads before this column's FMA chain
      int xn2 = x0 + xi + 2;
      bool vx2 = (xn2 < WID) && (xi < 15);
      size_t o = (size_t)xn2*CH;
      n0 = (v0&&vx2) ? *(const bfv8*)(r0+o) : Z;
      n1 = vx2       ? *(const bfv8*)(r1+o) : Z;
      n2 = (v2&&vx2) ? *(const bfv8*)(r2+o) : Z;
    }
    float acc[8];
#pragma unroll
    for (int j=0;j<8;++j) acc[j] = bb[j];
#pragma unroll
    for (int j=0;j<8;++j){
      acc[j] += wv[0][j]*b2f(w00[j]);
      acc[j] += wv[1][j]*b2f(w01[j]);
      acc[j] += wv[2][j]*b2f(w02[j]);
      acc[j] += wv[3][j]*b2f(w10[j]);
      acc[j] += wv[4][j]*b2f(w11[j]);
      acc[j] += wv[5][j]*b2f(w12[j]);
      acc[j] += wv[6][j]*b2f(w20[j]);
      acc[j] += wv[7][j]*b2f(w21[j]);
      acc[j] += wv[8][j]*b2f(w22[j]);
    }
    bfv8 st;
#pragma unroll
    for (int j=0;j<8;++j) st[j] = f2b(acc[j]);
    *(bfv8*)(O + ib + ((size_t)y*WID + x0 + xi)*CH + g*8) = st;
    w00=w01; w01=w02;
    w10=w11; w11=w12;
    w20=w21; w21=w22;
  }
}

// ---------------- K_attn v4: swapped-operand scores (S^T) and PV (o^T) ----------------
// Scores: MFMA(nb, af) -> lane holds S[m=l15][v = nt*16+lg*4+r] => in-lane rowsums,
// packed bfv4 P writes. PV: MFMA(vt, aa) -> lane holds o[m=l15][c = nt*16+lg*4+r]
// => per-lane scalar deferred scale, packed bfv4 F staging. MFMA addresses identical to v3.
__global__ __launch_bounds__(256) void k_attn(
    const bf* __restrict__ Ql, const bf* __restrict__ Qr,
    const bf* __restrict__ Vl, const bf* __restrict__ Vr,
    bf* __restrict__ Fout)
{
  extern __shared__ char sm[];
  bf* vt = (bf*)sm;                          // [96][264] = 50,688 B
  bf* aq = (bf*)(sm + 96*264*2);             // 4 x [16][104] = 13,312 B
  float* rs = (float*)(sm + 96*264*2 + 4*16*104*2);  // [256] = 1,024 B
  const int tid=threadIdx.x, lane=tid&63, wid=tid>>6;
  const int l15=lane&15, lg=lane>>4;
  bf* aqw = aq + wid*(16*104);
  const int bh = blockIdx.x;
  const size_t qoff = (size_t)bh * (WID*CH);

#pragma unroll 1
  for (int phase=0; phase<2; ++phase) {
    const bf* msrc = phase ? Qr+qoff : Ql+qoff;
    const bf* nsrc = phase ? Ql+qoff : Qr+qoff;
    const bf* V    = (phase ? Vl : Vr) + qoff;
    const int outoff = phase ? CH : 0;
    if (phase) {
      __syncthreads();               // phase-0 vt/aq reads + rs writes done
      rs[tid] = SCALE / rs[tid];     // rs -> fw table
    }
    { // stage V^T
      const bfv8* src = (const bfv8*)(V + (size_t)tid*CH);
#pragma unroll
      for (int i=0;i<12;++i){
        bfv8 v8 = src[i];
#pragma unroll
        for (int j=0;j<8;++j) vt[(i*8+j)*264 + tid] = v8[j];
      }
    }
    __syncthreads();                 // vt ready (+ fw published)

#pragma unroll 1
    for (int qp=0; qp<2; ++qp){
      bfv8 af2[2][3];
#pragma unroll
      for (int q01=0;q01<2;++q01){
        const int m0 = (qp*2+q01)*64 + wid*16;
#pragma unroll
        for (int ks=0;ks<3;++ks)
          af2[q01][ks] = *(const bfv8*)(msrc + (size_t)(m0+l15)*CH + ks*32 + lg*8);
      }
      f32x4 o[2][6];
#pragma unroll
      for (int q01=0;q01<2;++q01)
#pragma unroll
        for (int nt=0;nt<6;++nt) o[q01][nt]=(f32x4){0.f,0.f,0.f,0.f};
      float rsum2[2]={0.f,0.f};

#pragma unroll 1
      for (int c4=0;c4<4;++c4){
        bfv8 nb[4][3];
#pragma unroll
        for (int nt=0;nt<4;++nt)
#pragma unroll
          for (int ks=0;ks<3;++ks)
            nb[nt][ks] = *(const bfv8*)(nsrc + (size_t)(c4*64+nt*16+l15)*CH + ks*32+lg*8);
        f32x4 fwv4[4];
        if (phase){
#pragma unroll
          for (int nt=0;nt<4;++nt)
            fwv4[nt] = *(const f32x4*)(rs + c4*64 + nt*16 + lg*4);
        }
#pragma unroll
        for (int q01=0;q01<2;++q01){
          // ---- scores chunk (SWAPPED): lane holds S[m=l15][v=nt*16+lg*4+r] ----
          f32x4 acc[4];
#pragma unroll
          for (int nt=0;nt<4;++nt) acc[nt]=(f32x4){0.f,0.f,0.f,0.f};
#pragma unroll
          for (int ks=0;ks<3;++ks)
#pragma unroll
            for (int nt=0;nt<4;++nt)
              acc[nt]=MFMA16(nb[nt][ks], af2[q01][ks], acc[nt]);
          // ---- exp -> packed bfv4 into wave-private aq ----
          if (phase==0){
#pragma unroll
            for (int nt=0;nt<4;++nt){
              float e0=__expf(acc[nt][0]), e1=__expf(acc[nt][1]);
              float e2=__expf(acc[nt][2]), e3=__expf(acc[nt][3]);
              rsum2[q01] += (e0+e1)+(e2+e3);
              *(bfv4*)(aqw + l15*104 + nt*16 + lg*4) = pack4(e0,e1,e2,e3);
            }
          } else {
#pragma unroll
            for (int nt=0;nt<4;++nt){
              float e0=__expf(acc[nt][0])*fwv4[nt][0];
              float e1=__expf(acc[nt][1])*fwv4[nt][1];
              float e2=__expf(acc[nt][2])*fwv4[nt][2];
              float e3=__expf(acc[nt][3])*fwv4[nt][3];
              *(bfv4*)(aqw + l15*104 + nt*16 + lg*4) = pack4(e0,e1,e2,e3);
            }
          }
          // ---- PV partial (SWAPPED): o^T, lane holds o[m=l15][c=nt*16+lg*4+r] ----
#pragma unroll
          for (int ks=0;ks<2;++ks){
            bfv8 aa = *(const bfv8*)(aqw + l15*104 + ks*32 + lg*8);
#pragma unroll
            for (int nt=0;nt<6;++nt)
              o[q01][nt]=MFMA16(
                *(const bfv8*)(vt + (nt*16+l15)*264 + c4*64 + ks*32 + lg*8),
                aa, o[q01][nt]);
          }
        }
      }
      // ---- finalize: per-lane scalar deferred scale, packed stage, coalesced store ----
#pragma unroll
      for (int q01=0;q01<2;++q01){
        const int m0 = (qp*2+q01)*64 + wid*16;
        float sc;
        if (phase==0){
          float rsv = rsum2[q01];
          rsv += __shfl_xor(rsv, 16, 64);
          rsv += __shfl_xor(rsv, 32, 64);
          if (lane < 16) rs[m0 + l15] = rsv;   // raw rowsum for phase-1 fw
          sc = SCALE / rsv;
        } else sc = 1.f;
#pragma unroll
        for (int nt=0;nt<6;++nt)
          *(bfv4*)(aqw + l15*104 + nt*16 + lg*4)
            = pack4(o[q01][nt][0]*sc, o[q01][nt][1]*sc,
                    o[q01][nt][2]*sc, o[q01][nt][3]*sc);
        const size_t pbase=(size_t)bh*WID + m0;
#pragma unroll
        for (int i=0;i<3;++i){
          int u=lane+64*i; int gr=u/12, sg=u%12;
          *(bfv8*)(Fout + (pbase+gr)*192 + outoff + sg*8)
            = *(const bfv8*)(aqw + gr*104 + sg*8);
        }
      }
    }
  }
}

// ---------------- K_wprep ----------------
__global__ __launch_bounds__(256) void k_wprep(
    const float* __restrict__ L, const float* __restrict__ lb,
    const float* __restrict__ R, const float* __restrict__ rb,
    const float* __restrict__ D, const float* __restrict__ db,
    const float* __restrict__ beta, const float* __restrict__ gamma,
    bf* __restrict__ Wcat, float* __restrict__ bv)
{
  const int o = blockIdx.x;
  const int tid = threadIdx.x;
  for (int k = tid; k < 384; k += 256){
    float v;
    if (k < 192) v = D[o*192 + k];
    else if (k < 288){
      int c = k - 192; float s = 0.f;
      for (int m=0;m<96;++m) s += D[o*192+m]*beta[m]*L[m*96+c];
      v = s;
    } else {
      int c = k - 288; float s = 0.f;
      for (int m=0;m<96;++m) s += D[o*192+96+m]*gamma[m]*R[m*96+c];
      v = s;
    }
    Wcat[o*384+k] = f2b(v);
  }
  if (tid == 0){
    float s = db[o];
    for (int m=0;m<96;++m) s += D[o*192+m]*beta[m]*lb[m] + D[o*192+96+m]*gamma[m]*rb[m];
    bv[o] = s;
  }
}

// ---------------- K_fuse: out = [x_l|x_r|F1|F2] @ Wcat + b', weights-as-A (f32x4 stores) ----------------
__global__ __launch_bounds__(256) void k_fuse(
    const float* __restrict__ I1, const float* __restrict__ I2,
    const bf* F, const bf* __restrict__ Wcat, const float* __restrict__ bv,
    float* OUT)
{
  extern __shared__ bf fls[];   // [128][200]
  const int tid=threadIdx.x, lane=tid&63, wv=tid>>6;
  const int l15=lane&15, lg=lane>>4;
  const int half = wv&1, pair = wv>>1;
  const size_t p0 = (size_t)blockIdx.x * 128;

  {
    const int row = tid>>1, seg = (tid&1)*96;
    const bf* fsrc = F + (p0+row)*192 + seg;
    bf* ldst = fls + row*200 + seg;
#pragma unroll
    for (int i=0;i<12;++i) *(bfv8*)(ldst + i*8) = *(const bfv8*)(fsrc + i*8);
  }

  bfv8 wf[12][3];
  f32x4 bias4[3];
#pragma unroll
  for (int j=0;j<3;++j){
    int c = (half*3+j)*16;
    bias4[j] = *(const f32x4*)(bv + c + lg*4);
#pragma unroll
    for (int kb=0;kb<12;++kb)
      wf[kb][j] = *(const bfv8*)(Wcat + (size_t)(c+l15)*384 + kb*32 + lg*8);
  }
  __syncthreads();

#pragma unroll
  for (int i=0;i<4;++i){
    const int mloc = (pair*4+i)*16;
    const size_t m0 = p0 + mloc;
    bfv8 a[12];
    const float* x1 = I1 + (m0+l15)*CH + lg*8;
    const float* x2 = I2 + (m0+l15)*CH + lg*8;
    const bf* fp = fls + (mloc+l15)*200 + lg*8;
#pragma unroll
    for (int ks=0;ks<3;++ks){
      a[ks]   = ld_cvt8(x1 + ks*32);
      a[3+ks] = ld_cvt8(x2 + ks*32);
      a[6+ks] = *(const bfv8*)(fp + ks*32);
      a[9+ks] = *(const bfv8*)(fp + 96 + ks*32);
    }
    f32x4 acc[3];
#pragma unroll
    for (int j=0;j<3;++j) acc[j]=bias4[j];
#pragma unroll
    for (int kb=0;kb<12;++kb)
#pragma unroll
      for (int j=0;j<3;++j)
        acc[j] = MFMA16(wf[kb][j], a[kb], acc[j]);   // A=W, B=[x|F]
#pragma unroll
    for (int j=0;j<3;++j)
      *(f32x4*)(OUT + (m0+l15)*CH + (half*3+j)*16 + lg*4) = acc[j];
  }
}

extern "C" void kernel_launch(void* const* d_in, const int* in_sizes, int n_in,
                              void* d_out, int out_size, void* d_ws, size_t ws_size,
                              hipStream_t stream)
{
  (void)in_sizes; (void)n_in; (void)out_size; (void)ws_size;
  const float* I1 = (const float*)d_in[0];
  const float* I2 = (const float*)d_in[1];
  const float* se1_w = (const float*)d_in[4];
  const float* se1_b = (const float*)d_in[5];
  const float* se1_dw= (const float*)d_in[6];
  const float* se1_db= (const float*)d_in[7];
  const float* se2_w = (const float*)d_in[8];
  const float* se2_b = (const float*)d_in[9];
  const float* se2_dw= (const float*)d_in[10];
  const float* se2_db= (const float*)d_in[11];
  const float* lp1_w = (const float*)d_in[12];
  const float* lp1_b = (const float*)d_in[13];
  const float* lp1_dw= (const float*)d_in[14];
  const float* lp1_db= (const float*)d_in[15];
  const float* rp1_w = (const float*)d_in[16];
  const float* rp1_b = (const float*)d_in[17];
  const float* rp1_dw= (const float*)d_in[18];
  const float* rp1_db= (const float*)d_in[19];
  const float* lp2_w = (const float*)d_in[20];
  const float* lp2_b = (const float*)d_in[21];
  const float* rp2_w = (const float*)d_in[22];
  const float* rp2_b = (const float*)d_in[23];
  const float* down_w= (const float*)d_in[24];
  const float* down_b= (const float*)d_in[25];
  const float* beta  = (const float*)d_in[26];
  const float* gamma = (const float*)d_in[27];
  float* OUT = (float*)d_out;
  bf* Fbuf = (bf*)d_out;

  const size_t FIELD = (size_t)NB * HGT * WID * CH;
  bf* Ql = (bf*)d_ws;
  bf* Qr = Ql + FIELD;
  bf* Vl = Qr + FIELD;
  bf* Vr = Vl + FIELD;
  bf* Wcat = Vr + FIELD;
  float* bv = (float*)(Wcat + 96*384);
  bf* Cq = (bf*)d_out;
  bf* Cv = Cq + FIELD;

  dim3 blk(256,1,1);
  k_wprep<<<dim3(96,1,1), blk, 0, stream>>>(lp2_w, lp2_b, rp2_w, rp2_b,
        down_w, down_b, beta, gamma, Wcat, bv);
  k_c1x1<<<dim3(2048,1,1), blk, 0, stream>>>(I1, se1_w, se1_b, lp1_w, lp1_b, Cq, Cv);
  k_dw  <<<dim3(4,52,16),  blk, 0, stream>>>(Cq, Cv, se1_dw, se1_db, lp1_dw, lp1_db, Ql, Vl);
  k_c1x1<<<dim3(2048,1,1), blk, 0, stream>>>(I2, se2_w, se2_b, rp1_w, rp1_b, Cq, Cv);
  k_dw  <<<dim3(4,52,16),  blk, 0, stream>>>(Cq, Cv, se2_dw, se2_db, rp1_dw, rp1_db, Qr, Vr);
  k_attn<<<dim3(NB*HGT,1,1), blk, 96*264*2 + 4*16*104*2 + 256*4, stream>>>(
        Ql, Qr, Vl, Vr, Fbuf);
  k_fuse<<<dim3(4096,1,1), blk, 128*200*2, stream>>>(I1, I2, Fbuf, Wcat, bv, OUT);
}